// Round 11
// baseline (1643.328 us; speedup 1.0000x reference)
//
#include <hip/hip_runtime.h>
#include <hip/hip_bf16.h>
#include <math.h>

using f4 = __attribute__((ext_vector_type(4))) float;
using f16x = __attribute__((ext_vector_type(16))) float;
using sh4 = __attribute__((ext_vector_type(4))) short;
using sh8 = __attribute__((ext_vector_type(8))) short;

constexpr int cV = 32000, cC = 1024;
constexpr int cNH = 16, cNKV = 8, cHD = 64;
constexpr int cE = 8, cHID = 2728;
constexpr int cHIDP = 2752;              // K-pad for w2; 43*64 == cHIDP exactly
constexpr int cKS = 1408;                // w2 split-K boundary (both halves %64==0)
constexpr int cHIDR = 2816;              // row-pad for w1T/w3T slabs
constexpr int cB = 2, cT = 1024, cN = cB * cT;

__device__ inline float dot4(f4 a, f4 b) { return a[0]*b[0] + a[1]*b[1] + a[2]*b[2] + a[3]*b[3]; }

__device__ inline short f2bf(float f) {
  unsigned u = __builtin_bit_cast(unsigned, f);
  u += 0x7fff + ((u >> 16) & 1);          // RNE
  return (short)(u >> 16);
}
__device__ inline float bf2f(short s) {
  return __builtin_bit_cast(float, ((unsigned)(unsigned short)s) << 16);
}

// async global->LDS, 16B per lane; LDS dest is wave-uniform base + lane*16 (m97).
__device__ __forceinline__ void gl16(const void* g, void* l) {
  __builtin_amdgcn_global_load_lds((const __attribute__((address_space(1))) void*)g,
                                   (__attribute__((address_space(3))) void*)l, 16, 0, 0);
}

// ---------------- embedding gather ----------------
__global__ void embed_k(const int* __restrict__ idx, const float* __restrict__ wte,
                        float* __restrict__ x)
{
  int n = blockIdx.x, tid = threadIdx.x;
  size_t row = (size_t)idx[n] * cC;
  *(f4*)(x + (size_t)n * cC + tid * 4) = *(const f4*)(wte + row + tid * 4);
}

// ---------------- rmsnorm (fp32 in, bf16 out) ----------------
__global__ __launch_bounds__(256) void rmsnorm_k(const float* __restrict__ in,
                                                 const float* __restrict__ w,
                                                 short* __restrict__ out)
{
  int n = blockIdx.x, tid = threadIdx.x;
  f4 v = *(const f4*)(in + (size_t)n * cC + tid * 4);
  float s = dot4(v, v);
  #pragma unroll
  for (int off = 32; off; off >>= 1) s += __shfl_xor(s, off);
  __shared__ float red[4];
  if ((tid & 63) == 0) red[tid >> 6] = s;
  __syncthreads();
  float tot = red[0] + red[1] + red[2] + red[3];
  float inv = rsqrtf(tot * (1.0f / cC) + 1e-5f);
  f4 wv = *(const f4*)(w + tid * 4);
  f4 o = v * inv * wv;
  sh4 ov = { f2bf(o[0]), f2bf(o[1]), f2bf(o[2]), f2bf(o[3]) };
  *(sh4*)(out + (size_t)n * cC + tid * 4) = ov;
}

// ---- transpose + fp32->bf16: src[K][N] -> dst[N][Kp]; 64x64 tiles ----
__global__ __launch_bounds__(256) void convT_k(const float* __restrict__ src,
                                               short* __restrict__ dst,
                                               int K, int N, int Kp,
                                               size_t zsS, size_t zsD)
{
  src += (size_t)blockIdx.z * zsS;
  dst += (size_t)blockIdx.z * zsD;
  int k0 = blockIdx.x * 64, n0 = blockIdx.y * 64;
  __shared__ float T[64][65];
  int r = threadIdx.x >> 4;
  int cq = (threadIdx.x & 15) * 4;
  #pragma unroll
  for (int j = 0; j < 4; j++) {
    int k = k0 + r + j * 16;
    f4 v = {0.f, 0.f, 0.f, 0.f};
    if (k < K && n0 + cq < N)
      v = *(const f4*)(src + (size_t)k * N + n0 + cq);
    T[r + j * 16][cq + 0] = v[0]; T[r + j * 16][cq + 1] = v[1];
    T[r + j * 16][cq + 2] = v[2]; T[r + j * 16][cq + 3] = v[3];
  }
  __syncthreads();
  #pragma unroll
  for (int j = 0; j < 4; j++) {
    int n = n0 + r + j * 16;
    if (n < N) {
      sh4 ov = { f2bf(T[cq + 0][r + j * 16]), f2bf(T[cq + 1][r + j * 16]),
                 f2bf(T[cq + 2][r + j * 16]), f2bf(T[cq + 3][r + j * 16]) };
      *(sh4*)(dst + (size_t)n * Kp + k0 + cq) = ov;
    }
  }
}

// ====== bf16 GEMM 128x128, BK=64, global_load_lds, DBUF 2-phase (dense QKV/WO) ======
// EPI: 0 f32 store, 1 f32 +=, 2 bf16 qkv split-store.
template<int EPI>
__global__ __launch_bounds__(256, 2) void ggemm(
    const short* __restrict__ Ab, const short* __restrict__ Bt,
    float* __restrict__ Cf, short* __restrict__ Cq, short* __restrict__ Ck,
    short* __restrict__ Cv,
    int M, int Nc, int K, int lda, int ldb, int ldc)
{
  int m0 = blockIdx.x * 128;
  int n0 = blockIdx.y * 128;

  __shared__ short As[2 * 128 * 64];
  __shared__ short Bs[2 * 128 * 64];

  int tid = threadIdx.x, l = tid & 63, w = tid >> 6;
  int wr = w >> 1, wc = w & 1;
  int lq = l >> 3, ls = l & 7;

  const short* aptr[4];
  const short* bptr[4];
  #pragma unroll
  for (int i = 0; i < 4; i++) {
    int cA = w * 4 + i;
    int rA = cA * 8 + lq;
    int swz = (ls ^ (rA & 7)) * 8;
    aptr[i] = Ab + (size_t)(m0 + rA) * lda + swz;
    bptr[i] = Bt + (size_t)(n0 + rA) * ldb + swz;
  }

  f4 acc[4][4] = {};
  int fr = l & 15, fq = l >> 4;

  #pragma unroll
  for (int i = 0; i < 4; i++) {
    gl16(aptr[i], As + (w * 4 + i) * 512);
    gl16(bptr[i], Bs + (w * 4 + i) * 512);
  }
  __syncthreads();
  int cur = 0;
  for (int k0 = 0; k0 < K; k0 += 64) {
    if (k0 + 64 < K) {
      #pragma unroll
      for (int i = 0; i < 4; i++) {
        gl16(aptr[i] + k0 + 64, As + (cur ^ 1) * 8192 + (w * 4 + i) * 512);
        gl16(bptr[i] + k0 + 64, Bs + (cur ^ 1) * 8192 + (w * 4 + i) * 512);
      }
    }
    #pragma unroll
    for (int kk = 0; kk < 2; kk++) {
      sh8 af[4], bf[4];
      #pragma unroll
      for (int m = 0; m < 4; m++) {
        int r = wr * 64 + m * 16 + fr;
        af[m] = *(const sh8*)(As + cur * 8192 + r * 64 + (((kk * 4 + fq) ^ (r & 7)) * 8));
      }
      #pragma unroll
      for (int n = 0; n < 4; n++) {
        int r = wc * 64 + n * 16 + fr;
        bf[n] = *(const sh8*)(Bs + cur * 8192 + r * 64 + (((kk * 4 + fq) ^ (r & 7)) * 8));
      }
      #pragma unroll
      for (int m = 0; m < 4; m++)
        #pragma unroll
        for (int n = 0; n < 4; n++)
          acc[m][n] = __builtin_amdgcn_mfma_f32_16x16x32_bf16(af[m], bf[n], acc[m][n], 0, 0, 0);
    }
    __syncthreads();
    cur ^= 1;
  }

  int rq = fq * 4;
  #pragma unroll
  for (int m = 0; m < 4; m++) {
    #pragma unroll
    for (int i = 0; i < 4; i++) {
      size_t crow = (size_t)(m0 + wr * 64 + m * 16 + rq + i);
      #pragma unroll
      for (int n = 0; n < 4; n++) {
        int ncol = n0 + wc * 64 + n * 16 + fr;
        float vv = acc[m][n][i];
        if (EPI == 2) {
          short s = f2bf(vv);
          if (ncol < 1024)      Cq[crow * 1024 + ncol] = s;
          else if (ncol < 1536) Ck[crow * 512 + (ncol - 1024)] = s;
          else                  Cv[crow * 512 + (ncol - 1536)] = s;
        } else if (EPI == 0) Cf[crow * ldc + ncol] = vv;
        else                 Cf[crow * ldc + ncol] += vv;
      }
    }
  }
}

// ====== fused w1+w3 gather GEMM, tile 128m x 64n (grid-TLP 2x): bf16 acts ======
__global__ __launch_bounds__(256, 4) void gg_ff(
    const short* __restrict__ Ab, const short* __restrict__ B1t, const short* __restrict__ B3t,
    short* __restrict__ actsOut,
    const int* __restrict__ gidx, const int* __restrict__ gcnt)
{
  constexpr int K = cC, ldb = cC, lda = cC;
  int e = blockIdx.z;
  int Me = gcnt[e];
  const int* idxp = gidx + (size_t)e * cN;
  int m0 = blockIdx.x * 128;
  if (m0 >= Me) return;
  int n0 = blockIdx.y * 64;
  const short* B1e = B1t + (size_t)e * cHIDR * ldb;
  const short* B3e = B3t + (size_t)e * cHIDR * ldb;

  __shared__ short As[128 * 64];           // 16KB
  __shared__ short Bs1[64 * 64];           // 8KB
  __shared__ short Bs3[64 * 64];           // 8KB -> 32KB total

  int tid = threadIdx.x, l = tid & 63, w = tid >> 6;
  int wr = w >> 1, wc = w & 1;
  int lq = l >> 3, ls = l & 7;

  const short* aptr[4];
  const short* b1ptr[2];
  const short* b3ptr[2];
  #pragma unroll
  for (int i = 0; i < 4; i++) {
    int cA = w * 4 + i;
    int rA = cA * 8 + lq;
    int mr = m0 + rA; if (mr >= Me) mr = Me - 1;
    int token = idxp[mr] >> 1;
    aptr[i] = Ab + (size_t)token * lda + (ls ^ (rA & 7)) * 8;
  }
  #pragma unroll
  for (int i = 0; i < 2; i++) {
    int cB = w * 2 + i;
    int rB = cB * 8 + lq;                  // 0..63
    int swz = (ls ^ (rB & 7)) * 8;
    b1ptr[i] = B1e + (size_t)(n0 + rB) * ldb + swz;   // rows < 2816 (padded)
    b3ptr[i] = B3e + (size_t)(n0 + rB) * ldb + swz;
  }

  f4 acc1[4][2] = {}, acc3[4][2] = {};
  int fr = l & 15, fq = l >> 4;

  for (int k0 = 0; k0 < K; k0 += 64) {
    #pragma unroll
    for (int i = 0; i < 4; i++) gl16(aptr[i] + k0, As + (w * 4 + i) * 512);
    #pragma unroll
    for (int i = 0; i < 2; i++) {
      gl16(b1ptr[i] + k0, Bs1 + (w * 2 + i) * 512);
      gl16(b3ptr[i] + k0, Bs3 + (w * 2 + i) * 512);
    }
    __syncthreads();
    #pragma unroll
    for (int kk = 0; kk < 2; kk++) {
      sh8 af[4], bf1[2], bf3[2];
      #pragma unroll
      for (int m = 0; m < 4; m++) {
        int r = wr * 64 + m * 16 + fr;
        af[m] = *(const sh8*)(As + r * 64 + (((kk * 4 + fq) ^ (r & 7)) * 8));
      }
      #pragma unroll
      for (int n = 0; n < 2; n++) {
        int r = wc * 32 + n * 16 + fr;
        int so = ((kk * 4 + fq) ^ (r & 7)) * 8;
        bf1[n] = *(const sh8*)(Bs1 + r * 64 + so);
        bf3[n] = *(const sh8*)(Bs3 + r * 64 + so);
      }
      #pragma unroll
      for (int m = 0; m < 4; m++)
        #pragma unroll
        for (int n = 0; n < 2; n++) {
          acc1[m][n] = __builtin_amdgcn_mfma_f32_16x16x32_bf16(af[m], bf1[n], acc1[m][n], 0, 0, 0);
          acc3[m][n] = __builtin_amdgcn_mfma_f32_16x16x32_bf16(af[m], bf3[n], acc3[m][n], 0, 0, 0);
        }
    }
    __syncthreads();
  }

  int rq = fq * 4;
  #pragma unroll
  for (int m = 0; m < 4; m++) {
    #pragma unroll
    for (int i = 0; i < 4; i++) {
      int mrow = m0 + wr * 64 + m * 16 + rq + i;
      if (mrow >= Me) continue;
      size_t crow = (size_t)idxp[mrow] * cHIDP;
      #pragma unroll
      for (int n = 0; n < 2; n++) {
        int ncol = n0 + wc * 32 + n * 16 + fr;       // 43*64 = cHIDP exactly
        if (ncol < cHID) {
          float a1 = acc1[m][n][i], a3 = acc3[m][n][i];
          actsOut[crow + ncol] = f2bf(a1 / (1.f + __expf(-a1)) * a3);
        } else {
          actsOut[crow + ncol] = 0;                  // zero K-pad for w2
        }
      }
    }
  }
}

// ====== w2 gather GEMM, tile 128m x 64n, split-K=2, weighted atomicAdd into x ======
// z = e*2 + half. A = acts [slot][cHIDP], B = w2T [n][cHIDP].
__global__ __launch_bounds__(256, 4) void gg_w2(
    const short* __restrict__ Ab, const short* __restrict__ Bt,
    float* __restrict__ x, const float* __restrict__ selw,
    const int* __restrict__ gidx, const int* __restrict__ gcnt)
{
  int e = blockIdx.z >> 1, half = blockIdx.z & 1;
  int kb   = half ? cKS : 0;
  int Kend = half ? cHIDP : cKS;
  int Me = gcnt[e];
  const int* idxp = gidx + (size_t)e * cN;
  int m0 = blockIdx.x * 128;
  if (m0 >= Me) return;
  int n0 = blockIdx.y * 64;
  const short* Bte = Bt + (size_t)e * 1024 * cHIDP;

  __shared__ short As[128 * 64];           // 16KB
  __shared__ short Bs[64 * 64];            // 8KB -> 24KB total

  int tid = threadIdx.x, l = tid & 63, w = tid >> 6;
  int wr = w >> 1, wc = w & 1;
  int lq = l >> 3, ls = l & 7;

  const short* aptr[4];
  const short* bptr[2];
  #pragma unroll
  for (int i = 0; i < 4; i++) {
    int cA = w * 4 + i;
    int rA = cA * 8 + lq;
    int mr = m0 + rA; if (mr >= Me) mr = Me - 1;
    aptr[i] = Ab + (size_t)idxp[mr] * cHIDP + (ls ^ (rA & 7)) * 8;
  }
  #pragma unroll
  for (int i = 0; i < 2; i++) {
    int cB = w * 2 + i;
    int rB = cB * 8 + lq;
    bptr[i] = Bte + (size_t)(n0 + rB) * cHIDP + (ls ^ (rB & 7)) * 8;
  }

  f4 acc[4][2] = {};
  int fr = l & 15, fq = l >> 4;

  for (int k0 = kb; k0 < Kend; k0 += 64) {
    #pragma unroll
    for (int i = 0; i < 4; i++) gl16(aptr[i] + k0, As + (w * 4 + i) * 512);
    #pragma unroll
    for (int i = 0; i < 2; i++) gl16(bptr[i] + k0, Bs + (w * 2 + i) * 512);
    __syncthreads();
    #pragma unroll
    for (int kk = 0; kk < 2; kk++) {
      sh8 af[4], bf[2];
      #pragma unroll
      for (int m = 0; m < 4; m++) {
        int r = wr * 64 + m * 16 + fr;
        af[m] = *(const sh8*)(As + r * 64 + (((kk * 4 + fq) ^ (r & 7)) * 8));
      }
      #pragma unroll
      for (int n = 0; n < 2; n++) {
        int r = wc * 32 + n * 16 + fr;
        bf[n] = *(const sh8*)(Bs + r * 64 + (((kk * 4 + fq) ^ (r & 7)) * 8));
      }
      #pragma unroll
      for (int m = 0; m < 4; m++)
        #pragma unroll
        for (int n = 0; n < 2; n++)
          acc[m][n] = __builtin_amdgcn_mfma_f32_16x16x32_bf16(af[m], bf[n], acc[m][n], 0, 0, 0);
    }
    __syncthreads();
  }

  int rq = fq * 4;
  #pragma unroll
  for (int m = 0; m < 4; m++) {
    #pragma unroll
    for (int i = 0; i < 4; i++) {
      int mrow = m0 + wr * 64 + m * 16 + rq + i;
      if (mrow >= Me) continue;
      size_t crow = (size_t)idxp[mrow];
      float sw = selw[crow];
      float* xr = x + (crow >> 1) * cC;
      #pragma unroll
      for (int n = 0; n < 2; n++) {
        int ncol = n0 + wc * 32 + n * 16 + fr;
        atomicAdd(xr + ncol, acc[m][n][i] * sw);
      }
    }
  }
}

// ---------------- RoPE in place on bf16 [N, nh*64] ----------------
__global__ void rope_k(short* __restrict__ buf, int nh)
{
  int gid = blockIdx.x * 256 + threadIdx.x;
  int i = gid & 31;
  int rest = gid >> 5;
  int h = rest % nh;
  int n = rest / nh;
  int t = n & (cT - 1);
  float fr = __expf(-(float)i * (9.210340371976184f / 32.f));
  float ang = (float)t * fr;
  float sn, cs;
  sincosf(ang, &sn, &cs);
  short* p = buf + (size_t)n * (nh * cHD) + h * cHD + 2 * i;
  float r0 = bf2f(p[0]), r1 = bf2f(p[1]);
  p[0] = f2bf(r0 * cs - r1 * sn);
  p[1] = f2bf(r0 * sn + r1 * cs);
}

// ======== MFMA flash attention (bf16 q/k/v): 64 q-rows, 2 waves x 32 ========
__global__ __launch_bounds__(128) void attn_k(const short* __restrict__ qb,
                                              const short* __restrict__ kb,
                                              const short* __restrict__ vb,
                                              short* __restrict__ yb)
{
  int h = blockIdx.y, b = blockIdx.z;
  int qt = (b == 1) ? (15 - blockIdx.x) : blockIdx.x;   // causal load balance
  int qb0 = qt * 64;
  int kvh = h >> 1;                        // n_rep = 2
  int tid = threadIdx.x, w = tid >> 6, l = tid & 63;
  int c = l & 31, g = l >> 5;

  __shared__ short Kl[64 * 64];
  __shared__ short Vt[64 * 64];
  __shared__ short Pl[2][32 * 64];

  sh8 aq[4];
  {
    const short* qp = qb + (size_t)(b * cT + qb0 + w * 32 + c) * cC + h * cHD + g * 8;
    #pragma unroll
    for (int k = 0; k < 4; k++) aq[k] = *(const sh8*)(qp + k * 16);
  }

  float m[16], ll[16];
  f16x o0 = {}, o1 = {};
  #pragma unroll
  for (int i = 0; i < 16; i++) { m[i] = -1e30f; ll[i] = 0.f; }

  for (int kt = 0; kt <= qb0; kt += 64) {
    __syncthreads();
    #pragma unroll
    for (int i = 0; i < 4; i++) {
      int cK = w * 4 + i;
      int rK = cK * 8 + (l >> 3);
      const short* src = kb + (size_t)(b * cT + kt + rK) * 512 + kvh * 64
                       + (((l & 7) ^ (rK & 7)) * 8);
      gl16(src, Kl + cK * 512);
    }
    {
      int p = tid & 31, dh = tid >> 5;
      const short* v0 = vb + (size_t)(b * cT + kt + 2 * p) * 512 + kvh * 64 + dh * 16;
      const short* v1 = v0 + 512;
      sh8 a0 = *(const sh8*)v0, a1 = *(const sh8*)(v0 + 8);
      sh8 c0 = *(const sh8*)v1, c1 = *(const sh8*)(v1 + 8);
      #pragma unroll
      for (int j = 0; j < 16; j++) {
        int d = dh * 16 + j;
        unsigned lo = (unsigned)(unsigned short)(j < 8 ? a0[j] : a1[j - 8]);
        unsigned hi = (unsigned)(unsigned short)(j < 8 ? c0[j] : c1[j - 8]);
        *(unsigned*)((char*)Vt + d * 128 + ((p * 4) ^ ((d & 7) << 4))) = lo | (hi << 16);
      }
    }
    __syncthreads();

    f16x s0 = {}, s1 = {};
    #pragma unroll
    for (int k = 0; k < 4; k++) {
      int o16 = k * 2 + g;
      sh8 b0 = *(sh8*)((char*)Kl + c * 128 + ((o16 ^ (c & 7)) * 16));
      sh8 b1 = *(sh8*)((char*)Kl + (32 + c) * 128 + ((o16 ^ ((32 + c) & 7)) * 16));
      s0 = __builtin_amdgcn_mfma_f32_32x32x16_bf16(aq[k], b0, s0, 0, 0, 0);
      s1 = __builtin_amdgcn_mfma_f32_32x32x16_bf16(aq[k], b1, s1, 0, 0, 0);
    }
    #pragma unroll
    for (int i = 0; i < 16; i++) { s0[i] *= 0.125f; s1[i] *= 0.125f; }

    if (kt + 63 > qb0 + w * 32) {
      #pragma unroll
      for (int i = 0; i < 16; i++) {
        int r = qb0 + w * 32 + (i & 3) + 8 * (i >> 2) + 4 * g;
        if (kt + c > r)      s0[i] = -1e30f;
        if (kt + 32 + c > r) s1[i] = -1e30f;
      }
    }

    #pragma unroll
    for (int i = 0; i < 16; i++) {
      float mt = fmaxf(s0[i], s1[i]);
      #pragma unroll
      for (int off = 1; off < 32; off <<= 1) mt = fmaxf(mt, __shfl_xor(mt, off));
      float mn = fmaxf(m[i], mt);
      float rs = __expf(m[i] - mn);
      m[i] = mn;
      float p0 = __expf(s0[i] - mn);
      float p1 = __expf(s1[i] - mn);
      s0[i] = p0; s1[i] = p1;
      float ps = p0 + p1;
      #pragma unroll
      for (int off = 1; off < 32; off <<= 1) ps += __shfl_xor(ps, off);
      ll[i] = ll[i] * rs + ps;
      o0[i] *= rs; o1[i] *= rs;
    }

    #pragma unroll
    for (int i = 0; i < 16; i++) {
      int r = (i & 3) + 8 * (i >> 2) + 4 * g;
      *(short*)((char*)Pl[w] + r * 128 + ((c * 2) ^ ((r & 7) << 4)))        = f2bf(s0[i]);
      *(short*)((char*)Pl[w] + r * 128 + (((32 + c) * 2) ^ ((r & 7) << 4))) = f2bf(s1[i]);
    }

    #pragma unroll
    for (int k = 0; k < 4; k++) {
      int o16 = k * 2 + g;
      sh8 ap  = *(sh8*)((char*)Pl[w] + c * 128 + ((o16 ^ (c & 7)) * 16));
      sh8 bv0 = *(sh8*)((char*)Vt + c * 128 + ((o16 ^ (c & 7)) * 16));
      sh8 bv1 = *(sh8*)((char*)Vt + (32 + c) * 128 + ((o16 ^ ((32 + c) & 7)) * 16));
      o0 = __builtin_amdgcn_mfma_f32_32x32x16_bf16(ap, bv0, o0, 0, 0, 0);
      o1 = __builtin_amdgcn_mfma_f32_32x32x16_bf16(ap, bv1, o1, 0, 0, 0);
    }
  }

  #pragma unroll
  for (int i = 0; i < 16; i++) {
    int r = qb0 + w * 32 + (i & 3) + 8 * (i >> 2) + 4 * g;
    float inv = 1.0f / ll[i];
    short* yp = yb + (size_t)(b * cT + r) * cC + h * cHD;
    yp[c]      = f2bf(o0[i] * inv);
    yp[32 + c] = f2bf(o1[i] * inv);
  }
}

// ---------------- gate (bf16 h): top-2 + softmax + atomic routing ----------------
__global__ __launch_bounds__(256) void gate_k(const short* __restrict__ h2,
                                              const float* __restrict__ gw,
                                              float* __restrict__ selw,
                                              int* __restrict__ cnt, int* __restrict__ elist)
{
  int wv = threadIdx.x >> 6, lane = threadIdx.x & 63;
  int n = blockIdx.x * 4 + wv;
  float acc[8] = {0.f, 0.f, 0.f, 0.f, 0.f, 0.f, 0.f, 0.f};
  for (int c = lane; c < cC; c += 64) {
    float hv = bf2f(h2[(size_t)n * cC + c]);
    f4 g0 = *(const f4*)(gw + c * 8);
    f4 g1 = *(const f4*)(gw + c * 8 + 4);
    acc[0] = fmaf(hv, g0[0], acc[0]); acc[1] = fmaf(hv, g0[1], acc[1]);
    acc[2] = fmaf(hv, g0[2], acc[2]); acc[3] = fmaf(hv, g0[3], acc[3]);
    acc[4] = fmaf(hv, g1[0], acc[4]); acc[5] = fmaf(hv, g1[1], acc[5]);
    acc[6] = fmaf(hv, g1[2], acc[6]); acc[7] = fmaf(hv, g1[3], acc[7]);
  }
  #pragma unroll
  for (int e = 0; e < 8; e++)
    #pragma unroll
    for (int off = 32; off; off >>= 1) acc[e] += __shfl_xor(acc[e], off);
  if (lane == 0) {
    int i0 = 0; float m0 = acc[0];
    #pragma unroll
    for (int e = 1; e < 8; e++) if (acc[e] > m0) { m0 = acc[e]; i0 = e; }
    int i1 = -1; float m1 = -INFINITY;
    #pragma unroll
    for (int e = 0; e < 8; e++) if (e != i0 && acc[e] > m1) { m1 = acc[e]; i1 = e; }
    float e1 = expf(m1 - m0);
    selw[n * 2]     = 1.f / (1.f + e1);
    selw[n * 2 + 1] = e1 / (1.f + e1);
    int pos0 = atomicAdd(&cnt[i0], 1); elist[(size_t)i0 * cN + pos0] = n * 2;
    int pos1 = atomicAdd(&cnt[i1], 1); elist[(size_t)i1 * cN + pos1] = n * 2 + 1;
  }
}

// ---------------- logits (bf16 h, fp32 wte) ----------------
__global__ __launch_bounds__(256) void logits_k(const short* __restrict__ hf,
                                                const float* __restrict__ wte,
                                                float* __restrict__ out)
{
  int wv = threadIdx.x >> 6, lane = threadIdx.x & 63;
  int v = blockIdx.x * 4 + wv;
  const float* wrow = wte + (size_t)v * cC;
  const short* r0 = hf + (size_t)(cT - 1) * cC;
  const short* r1 = hf + (size_t)(2 * cT - 1) * cC;
  float a0 = 0.f, a1 = 0.f;
  for (int c = lane * 4; c < cC; c += 256) {
    f4 w4 = *(const f4*)(wrow + c);
    sh4 s0 = *(const sh4*)(r0 + c);
    sh4 s1 = *(const sh4*)(r1 + c);
    #pragma unroll
    for (int j = 0; j < 4; j++) {
      a0 = fmaf(w4[j], bf2f(s0[j]), a0);
      a1 = fmaf(w4[j], bf2f(s1[j]), a1);
    }
  }
  #pragma unroll
  for (int off = 32; off; off >>= 1) { a0 += __shfl_xor(a0, off); a1 += __shfl_xor(a1, off); }
  if (lane == 0) { out[v] = a0; out[cV + v] = a1; }
}

// =======================================================================
extern "C" void kernel_launch(void* const* d_in, const int* in_sizes, int n_in,
                              void* d_out, int out_size, void* d_ws, size_t ws_size,
                              hipStream_t stream)
{
  (void)in_sizes; (void)n_in; (void)out_size;
  const int*   idx  = (const int*)  d_in[0];
  const float* wte  = (const float*)d_in[1];
  const float* ln1w = (const float*)d_in[2];
  const float* p_wq = (const float*)d_in[3];
  const float* p_wk = (const float*)d_in[4];
  const float* p_wv = (const float*)d_in[5];
  const float* p_wo = (const float*)d_in[6];
  const float* ln2w = (const float*)d_in[7];
  const float* gw   = (const float*)d_in[8];
  const float* w1   = (const float*)d_in[9];
  const float* w2   = (const float*)d_in[10];
  const float* w3   = (const float*)d_in[11];
  const float* lnfw = (const float*)d_in[12];
  float* out = (float*)d_out;

  char* base = (char*)d_ws;
  size_t off = 0;
  auto alloc = [&](size_t bytes) { char* r = base + off; off = (off + bytes + 255) & ~(size_t)255; return r; };

  float* x     = (float*)alloc((size_t)cN * cC * 4);
  short* h     = (short*)alloc((size_t)cN * cC * 2);
  short* q     = (short*)alloc((size_t)cN * cC * 2);
  short* kbuf  = (short*)alloc((size_t)cN * 512 * 2);
  short* vbuf  = (short*)alloc((size_t)cN * 512 * 2);
  short* y     = (short*)alloc((size_t)cN * cC * 2);
  short* acts  = (short*)alloc((size_t)cN * 2 * cHIDP * 2);
  float* selw  = (float*)alloc((size_t)cN * 2 * 4);
  int*   cnt   = (int*)  alloc(64);
  int*   elist = (int*)  alloc((size_t)cE * cN * 4);
  short* wqkvT = (short*)alloc((size_t)2 * 2048 * 1024 * 2);
  short* woT   = (short*)alloc((size_t)2 * 1024 * 1024 * 2);
  short* w1T   = (short*)alloc((size_t)cE * cHIDR * 1024 * 2);
  short* w3T   = (short*)alloc((size_t)cE * cHIDR * 1024 * 2);
  short* w2T   = (short*)alloc((size_t)cE * 1024 * cHIDP * 2);
  if (ws_size < off) return;   // ~183 MB

  embed_k<<<cN, 256, 0, stream>>>(idx, wte, x);
  convT_k<<<dim3(16, 16, 2), 256, 0, stream>>>(p_wq, wqkvT, 1024, 1024, 1024,
      (size_t)1024 * 1024, (size_t)2048 * 1024);
  convT_k<<<dim3(16, 8, 2), 256, 0, stream>>>(p_wk, wqkvT + (size_t)1024 * 1024, 1024, 512, 1024,
      (size_t)1024 * 512, (size_t)2048 * 1024);
  convT_k<<<dim3(16, 8, 2), 256, 0, stream>>>(p_wv, wqkvT + (size_t)1536 * 1024, 1024, 512, 1024,
      (size_t)1024 * 512, (size_t)2048 * 1024);
  convT_k<<<dim3(16, 16, 2), 256, 0, stream>>>(p_wo, woT, 1024, 1024, 1024,
      (size_t)1024 * 1024, (size_t)1024 * 1024);

  for (int l = 0; l < 2; l++) {
    // ---- attention ----
    rmsnorm_k<<<cN, 256, 0, stream>>>(x, ln1w + (size_t)l * cC, h);
    ggemm<2><<<dim3(16, 16), 256, 0, stream>>>(h, wqkvT + (size_t)l * 2048 * 1024,
        nullptr, q, kbuf, vbuf, cN, 2048, 1024, 1024, 1024, 0);
    rope_k<<<(cN * cNH * 32) / 256, 256, 0, stream>>>(q, cNH);
    rope_k<<<(cN * cNKV * 32) / 256, 256, 0, stream>>>(kbuf, cNKV);
    attn_k<<<dim3(16, cNH, cB), 128, 0, stream>>>(q, kbuf, vbuf, y);
    ggemm<1><<<dim3(16, 8), 256, 0, stream>>>(y, woT + (size_t)l * 1024 * 1024,
        x, nullptr, nullptr, nullptr, cN, 1024, 1024, 1024, 1024, 1024);

    // ---- MoE ----
    rmsnorm_k<<<cN, 256, 0, stream>>>(x, ln2w + (size_t)l * cC, h);
    hipMemsetAsync(cnt, 0, cE * sizeof(int), stream);
    gate_k<<<cN / 4, 256, 0, stream>>>(h, gw + (size_t)l * cC * cE, selw, cnt, elist);
    convT_k<<<dim3(16, 43, 8), 256, 0, stream>>>(w1 + (size_t)l * cE * cC * cHID, w1T,
        1024, cHID, 1024, (size_t)1024 * cHID, (size_t)cHIDR * 1024);
    convT_k<<<dim3(16, 43, 8), 256, 0, stream>>>(w3 + (size_t)l * cE * cC * cHID, w3T,
        1024, cHID, 1024, (size_t)1024 * cHID, (size_t)cHIDR * 1024);
    gg_ff<<<dim3(16, 43, 8), 256, 0, stream>>>(h, w1T, w3T, acts, elist, cnt);
    convT_k<<<dim3(43, 16, 8), 256, 0, stream>>>(w2 + (size_t)l * cE * cHID * cC, w2T,
        cHID, 1024, cHIDP, (size_t)cHID * 1024, (size_t)1024 * cHIDP);
    gg_w2<<<dim3(16, 16, 16), 256, 0, stream>>>(acts, w2T, x, selw, elist, cnt);
  }

  rmsnorm_k<<<cN, 256, 0, stream>>>(x, lnfw, h);
  logits_k<<<cV / 4, 256, 0, stream>>>(h, wte, out);
}

// Round 12
// 1262.752 us; speedup vs baseline: 1.3014x; 1.3014x over previous
//
#include <hip/hip_runtime.h>
#include <hip/hip_bf16.h>
#include <math.h>

using f4 = __attribute__((ext_vector_type(4))) float;
using f16x = __attribute__((ext_vector_type(16))) float;
using sh4 = __attribute__((ext_vector_type(4))) short;
using sh8 = __attribute__((ext_vector_type(8))) short;

constexpr int cV = 32000, cC = 1024;
constexpr int cNH = 16, cNKV = 8, cHD = 64;
constexpr int cE = 8, cHID = 2728;
constexpr int cHIDP = 2752;              // K-pad for w2 (multiple of 64)
constexpr int cKS = 1408;                // w2 split-K boundary (both halves %64==0)
constexpr int cHIDR = 2816;              // row-pad for w1T/w3T slabs
constexpr int cB = 2, cT = 1024, cN = cB * cT;

__device__ inline float dot4(f4 a, f4 b) { return a[0]*b[0] + a[1]*b[1] + a[2]*b[2] + a[3]*b[3]; }

__device__ inline short f2bf(float f) {
  unsigned u = __builtin_bit_cast(unsigned, f);
  u += 0x7fff + ((u >> 16) & 1);          // RNE
  return (short)(u >> 16);
}
__device__ inline float bf2f(short s) {
  return __builtin_bit_cast(float, ((unsigned)(unsigned short)s) << 16);
}

// async global->LDS, 16B per lane; LDS dest is wave-uniform base + lane*16 (m97).
__device__ __forceinline__ void gl16(const void* g, void* l) {
  __builtin_amdgcn_global_load_lds((const __attribute__((address_space(1))) void*)g,
                                   (__attribute__((address_space(3))) void*)l, 16, 0, 0);
}

// ---------------- embedding gather ----------------
__global__ void embed_k(const int* __restrict__ idx, const float* __restrict__ wte,
                        float* __restrict__ x)
{
  int n = blockIdx.x, tid = threadIdx.x;
  size_t row = (size_t)idx[n] * cC;
  *(f4*)(x + (size_t)n * cC + tid * 4) = *(const f4*)(wte + row + tid * 4);
}

// ---------------- rmsnorm (fp32 in, bf16 out) ----------------
__global__ __launch_bounds__(256) void rmsnorm_k(const float* __restrict__ in,
                                                 const float* __restrict__ w,
                                                 short* __restrict__ out)
{
  int n = blockIdx.x, tid = threadIdx.x;
  f4 v = *(const f4*)(in + (size_t)n * cC + tid * 4);
  float s = dot4(v, v);
  #pragma unroll
  for (int off = 32; off; off >>= 1) s += __shfl_xor(s, off);
  __shared__ float red[4];
  if ((tid & 63) == 0) red[tid >> 6] = s;
  __syncthreads();
  float tot = red[0] + red[1] + red[2] + red[3];
  float inv = rsqrtf(tot * (1.0f / cC) + 1e-5f);
  f4 wv = *(const f4*)(w + tid * 4);
  f4 o = v * inv * wv;
  sh4 ov = { f2bf(o[0]), f2bf(o[1]), f2bf(o[2]), f2bf(o[3]) };
  *(sh4*)(out + (size_t)n * cC + tid * 4) = ov;
}

// ------- transpose + fp32->bf16: src[K][N] -> dst[N][Kp], zero-fill k in [K,Kp) -------
__global__ __launch_bounds__(256) void convT_k(const float* __restrict__ src,
                                               short* __restrict__ dst,
                                               int K, int N, int Kp,
                                               size_t zsS, size_t zsD)
{
  src += (size_t)blockIdx.z * zsS;
  dst += (size_t)blockIdx.z * zsD;
  int k0 = blockIdx.x * 32, n0 = blockIdx.y * 32;
  __shared__ float T[32][33];
  int r = threadIdx.x >> 3, cq = (threadIdx.x & 7) * 4;
  f4 v = {0.f, 0.f, 0.f, 0.f};
  if (k0 + r < K && n0 + cq < N)
    v = *(const f4*)(src + (size_t)(k0 + r) * N + n0 + cq);
  T[r][cq + 0] = v[0]; T[r][cq + 1] = v[1]; T[r][cq + 2] = v[2]; T[r][cq + 3] = v[3];
  __syncthreads();
  int n = n0 + r;
  if (n < N) {
    sh4 ov = { f2bf(T[cq + 0][r]), f2bf(T[cq + 1][r]), f2bf(T[cq + 2][r]), f2bf(T[cq + 3][r]) };
    *(sh4*)(dst + (size_t)n * Kp + k0 + cq) = ov;
  }
}

// ====== m97-style bf16 GEMM (dense): 128x128 tile, BK=64, global_load_lds ======
// EPI: 0 f32 store, 1 f32 +=, 2 bf16 qkv split-store.
template<int EPI>
__global__ __launch_bounds__(256, 3) void ggemm(
    const short* __restrict__ Ab, const short* __restrict__ Bt,
    float* __restrict__ Cf, short* __restrict__ Cq, short* __restrict__ Ck,
    short* __restrict__ Cv,
    int M, int Nc, int K, int lda, int ldb, int ldc)
{
  int m0 = blockIdx.x * 128;
  int n0 = blockIdx.y * 128;

  __shared__ short As[128 * 64];
  __shared__ short Bs[128 * 64];

  int tid = threadIdx.x, l = tid & 63, w = tid >> 6;
  int wr = w >> 1, wc = w & 1;
  int lq = l >> 3, ls = l & 7;

  const short* aptr[4];
  const short* bptr[4];
  #pragma unroll
  for (int i = 0; i < 4; i++) {
    int cA = w * 4 + i;
    int rA = cA * 8 + lq;
    int swz = (ls ^ (rA & 7)) * 8;
    aptr[i] = Ab + (size_t)(m0 + rA) * lda + swz;
    bptr[i] = Bt + (size_t)(n0 + rA) * ldb + swz;
  }

  f4 acc[4][4] = {};
  int fr = l & 15, fq = l >> 4;

  for (int k0 = 0; k0 < K; k0 += 64) {
    #pragma unroll
    for (int i = 0; i < 4; i++) {
      gl16(aptr[i] + k0, As + (w * 4 + i) * 512);
      gl16(bptr[i] + k0, Bs + (w * 4 + i) * 512);
    }
    __syncthreads();
    #pragma unroll
    for (int kk = 0; kk < 2; kk++) {
      sh8 af[4], bf[4];
      #pragma unroll
      for (int m = 0; m < 4; m++) {
        int r = wr * 64 + m * 16 + fr;
        af[m] = *(const sh8*)(As + r * 64 + (((kk * 4 + fq) ^ (r & 7)) * 8));
      }
      #pragma unroll
      for (int n = 0; n < 4; n++) {
        int r = wc * 64 + n * 16 + fr;
        bf[n] = *(const sh8*)(Bs + r * 64 + (((kk * 4 + fq) ^ (r & 7)) * 8));
      }
      #pragma unroll
      for (int m = 0; m < 4; m++)
        #pragma unroll
        for (int n = 0; n < 4; n++)
          acc[m][n] = __builtin_amdgcn_mfma_f32_16x16x32_bf16(af[m], bf[n], acc[m][n], 0, 0, 0);
    }
    __syncthreads();
  }

  int rq = fq * 4;
  #pragma unroll
  for (int m = 0; m < 4; m++) {
    #pragma unroll
    for (int i = 0; i < 4; i++) {
      size_t crow = (size_t)(m0 + wr * 64 + m * 16 + rq + i);
      #pragma unroll
      for (int n = 0; n < 4; n++) {
        int ncol = n0 + wc * 64 + n * 16 + fr;
        float vv = acc[m][n][i];
        if (EPI == 2) {
          short s = f2bf(vv);
          if (ncol < 1024)      Cq[crow * 1024 + ncol] = s;
          else if (ncol < 1536) Ck[crow * 512 + (ncol - 1024)] = s;
          else                  Cv[crow * 512 + (ncol - 1536)] = s;
        } else if (EPI == 0) Cf[crow * ldc + ncol] = vv;
        else                 Cf[crow * ldc + ncol] += vv;
      }
    }
  }
}

// ====== fused w1+w3 gather GEMM, tile 64m x 128n (2x grid TLP, healthy writes) ======
__global__ __launch_bounds__(256, 4) void gg_ff(
    const short* __restrict__ Ab, const short* __restrict__ B1t, const short* __restrict__ B3t,
    short* __restrict__ actsOut,
    const int* __restrict__ gidx, const int* __restrict__ gcnt)
{
  constexpr int K = cC, ldb = cC, lda = cC;
  int e = blockIdx.z;
  int Me = gcnt[e];
  const int* idxp = gidx + (size_t)e * cN;
  int m0 = blockIdx.x * 64;
  if (m0 >= Me) return;
  int n0 = blockIdx.y * 128;
  const short* B1e = B1t + (size_t)e * cHIDR * ldb;
  const short* B3e = B3t + (size_t)e * cHIDR * ldb;

  __shared__ short As[64 * 64];            // 8KB
  __shared__ short Bs1[128 * 64];          // 16KB
  __shared__ short Bs3[128 * 64];          // 16KB -> 40KB, 4 blocks/CU

  int tid = threadIdx.x, l = tid & 63, w = tid >> 6;
  int wr = w >> 1, wc = w & 1;
  int lq = l >> 3, ls = l & 7;

  const short* aptr[2];
  const short* b1ptr[4];
  const short* b3ptr[4];
  #pragma unroll
  for (int i = 0; i < 2; i++) {
    int cA = w * 2 + i;
    int rA = cA * 8 + lq;                  // 0..63
    int mr = m0 + rA; if (mr >= Me) mr = Me - 1;
    int token = idxp[mr] >> 1;
    aptr[i] = Ab + (size_t)token * lda + (ls ^ (rA & 7)) * 8;
  }
  #pragma unroll
  for (int i = 0; i < 4; i++) {
    int cB = w * 4 + i;
    int rB = cB * 8 + lq;                  // 0..127
    int swz = (ls ^ (rB & 7)) * 8;
    b1ptr[i] = B1e + (size_t)(n0 + rB) * ldb + swz;   // rows < cHIDR (padded)
    b3ptr[i] = B3e + (size_t)(n0 + rB) * ldb + swz;
  }

  f4 acc1[2][4] = {}, acc3[2][4] = {};
  int fr = l & 15, fq = l >> 4;

  for (int k0 = 0; k0 < K; k0 += 64) {
    #pragma unroll
    for (int i = 0; i < 2; i++) gl16(aptr[i] + k0, As + (w * 2 + i) * 512);
    #pragma unroll
    for (int i = 0; i < 4; i++) {
      gl16(b1ptr[i] + k0, Bs1 + (w * 4 + i) * 512);
      gl16(b3ptr[i] + k0, Bs3 + (w * 4 + i) * 512);
    }
    __syncthreads();
    #pragma unroll
    for (int kk = 0; kk < 2; kk++) {
      sh8 af[2], bf1[4], bf3[4];
      #pragma unroll
      for (int m = 0; m < 2; m++) {
        int r = wr * 32 + m * 16 + fr;
        af[m] = *(const sh8*)(As + r * 64 + (((kk * 4 + fq) ^ (r & 7)) * 8));
      }
      #pragma unroll
      for (int n = 0; n < 4; n++) {
        int r = wc * 64 + n * 16 + fr;
        int so = ((kk * 4 + fq) ^ (r & 7)) * 8;
        bf1[n] = *(const sh8*)(Bs1 + r * 64 + so);
        bf3[n] = *(const sh8*)(Bs3 + r * 64 + so);
      }
      #pragma unroll
      for (int m = 0; m < 2; m++)
        #pragma unroll
        for (int n = 0; n < 4; n++) {
          acc1[m][n] = __builtin_amdgcn_mfma_f32_16x16x32_bf16(af[m], bf1[n], acc1[m][n], 0, 0, 0);
          acc3[m][n] = __builtin_amdgcn_mfma_f32_16x16x32_bf16(af[m], bf3[n], acc3[m][n], 0, 0, 0);
        }
    }
    __syncthreads();
  }

  int rq = fq * 4;
  #pragma unroll
  for (int m = 0; m < 2; m++) {
    #pragma unroll
    for (int i = 0; i < 4; i++) {
      int mrow = m0 + wr * 32 + m * 16 + rq + i;
      if (mrow >= Me) continue;
      size_t crow = (size_t)idxp[mrow] * cHIDP;
      #pragma unroll
      for (int n = 0; n < 4; n++) {
        int ncol = n0 + wc * 64 + n * 16 + fr;
        if (ncol < cHID) {
          float a1 = acc1[m][n][i], a3 = acc3[m][n][i];
          actsOut[crow + ncol] = f2bf(a1 / (1.f + __expf(-a1)) * a3);
        } else if (ncol < cHIDP) {
          actsOut[crow + ncol] = 0;        // zero K-pad for w2
        }
      }
    }
  }
}

// ====== w2 gather GEMM, 64m x 128n, split-K=2, weighted atomicAdd into x ======
// z = e*2 + half. A = acts [slot][cHIDP], B = w2T [n][cHIDP].
__global__ __launch_bounds__(256, 4) void gg_w2(
    const short* __restrict__ Ab, const short* __restrict__ Bt,
    float* __restrict__ x, const float* __restrict__ selw,
    const int* __restrict__ gidx, const int* __restrict__ gcnt)
{
  int e = blockIdx.z >> 1, half = blockIdx.z & 1;
  int kb   = half ? cKS : 0;
  int Kend = half ? cHIDP : cKS;
  int Me = gcnt[e];
  const int* idxp = gidx + (size_t)e * cN;
  int m0 = blockIdx.x * 64;
  if (m0 >= Me) return;
  int n0 = blockIdx.y * 128;
  const short* Bte = Bt + (size_t)e * 1024 * cHIDP;

  __shared__ short As[64 * 64];            // 8KB
  __shared__ short Bs[128 * 64];           // 16KB -> 24KB

  int tid = threadIdx.x, l = tid & 63, w = tid >> 6;
  int wr = w >> 1, wc = w & 1;
  int lq = l >> 3, ls = l & 7;

  const short* aptr[2];
  const short* bptr[4];
  #pragma unroll
  for (int i = 0; i < 2; i++) {
    int cA = w * 2 + i;
    int rA = cA * 8 + lq;
    int mr = m0 + rA; if (mr >= Me) mr = Me - 1;
    aptr[i] = Ab + (size_t)idxp[mr] * cHIDP + (ls ^ (rA & 7)) * 8;
  }
  #pragma unroll
  for (int i = 0; i < 4; i++) {
    int cB = w * 4 + i;
    int rB = cB * 8 + lq;
    bptr[i] = Bte + (size_t)(n0 + rB) * cHIDP + (ls ^ (rB & 7)) * 8;
  }

  f4 acc[2][4] = {};
  int fr = l & 15, fq = l >> 4;

  for (int k0 = kb; k0 < Kend; k0 += 64) {
    #pragma unroll
    for (int i = 0; i < 2; i++) gl16(aptr[i] + k0, As + (w * 2 + i) * 512);
    #pragma unroll
    for (int i = 0; i < 4; i++) gl16(bptr[i] + k0, Bs + (w * 4 + i) * 512);
    __syncthreads();
    #pragma unroll
    for (int kk = 0; kk < 2; kk++) {
      sh8 af[2], bf[4];
      #pragma unroll
      for (int m = 0; m < 2; m++) {
        int r = wr * 32 + m * 16 + fr;
        af[m] = *(const sh8*)(As + r * 64 + (((kk * 4 + fq) ^ (r & 7)) * 8));
      }
      #pragma unroll
      for (int n = 0; n < 4; n++) {
        int r = wc * 64 + n * 16 + fr;
        bf[n] = *(const sh8*)(Bs + r * 64 + (((kk * 4 + fq) ^ (r & 7)) * 8));
      }
      #pragma unroll
      for (int m = 0; m < 2; m++)
        #pragma unroll
        for (int n = 0; n < 4; n++)
          acc[m][n] = __builtin_amdgcn_mfma_f32_16x16x32_bf16(af[m], bf[n], acc[m][n], 0, 0, 0);
    }
    __syncthreads();
  }

  int rq = fq * 4;
  #pragma unroll
  for (int m = 0; m < 2; m++) {
    #pragma unroll
    for (int i = 0; i < 4; i++) {
      int mrow = m0 + wr * 32 + m * 16 + rq + i;
      if (mrow >= Me) continue;
      size_t crow = (size_t)idxp[mrow];
      float sw = selw[crow];
      float* xr = x + (crow >> 1) * cC;
      #pragma unroll
      for (int n = 0; n < 4; n++) {
        int ncol = n0 + wc * 64 + n * 16 + fr;
        atomicAdd(xr + ncol, acc[m][n][i] * sw);
      }
    }
  }
}

// ---------------- RoPE in place on bf16 [N, nh*64] ----------------
__global__ void rope_k(short* __restrict__ buf, int nh)
{
  int gid = blockIdx.x * 256 + threadIdx.x;
  int i = gid & 31;
  int rest = gid >> 5;
  int h = rest % nh;
  int n = rest / nh;
  int t = n & (cT - 1);
  float fr = __expf(-(float)i * (9.210340371976184f / 32.f));
  float ang = (float)t * fr;
  float sn, cs;
  sincosf(ang, &sn, &cs);
  short* p = buf + (size_t)n * (nh * cHD) + h * cHD + 2 * i;
  float r0 = bf2f(p[0]), r1 = bf2f(p[1]);
  p[0] = f2bf(r0 * cs - r1 * sn);
  p[1] = f2bf(r0 * sn + r1 * cs);
}

// ======== MFMA flash attention (bf16 q/k/v): 64 q-rows, 2 waves x 32 ========
__global__ __launch_bounds__(128) void attn_k(const short* __restrict__ qb,
                                              const short* __restrict__ kb,
                                              const short* __restrict__ vb,
                                              short* __restrict__ yb)
{
  int h = blockIdx.y, b = blockIdx.z;
  int qt = (b == 1) ? (15 - blockIdx.x) : blockIdx.x;   // causal load balance
  int qb0 = qt * 64;
  int kvh = h >> 1;                        // n_rep = 2
  int tid = threadIdx.x, w = tid >> 6, l = tid & 63;
  int c = l & 31, g = l >> 5;

  __shared__ short Kl[64 * 64];
  __shared__ short Vt[64 * 64];
  __shared__ short Pl[2][32 * 64];

  sh8 aq[4];
  {
    const short* qp = qb + (size_t)(b * cT + qb0 + w * 32 + c) * cC + h * cHD + g * 8;
    #pragma unroll
    for (int k = 0; k < 4; k++) aq[k] = *(const sh8*)(qp + k * 16);
  }

  float m[16], ll[16];
  f16x o0 = {}, o1 = {};
  #pragma unroll
  for (int i = 0; i < 16; i++) { m[i] = -1e30f; ll[i] = 0.f; }

  for (int kt = 0; kt <= qb0; kt += 64) {
    __syncthreads();
    #pragma unroll
    for (int i = 0; i < 4; i++) {
      int cK = w * 4 + i;
      int rK = cK * 8 + (l >> 3);
      const short* src = kb + (size_t)(b * cT + kt + rK) * 512 + kvh * 64
                       + (((l & 7) ^ (rK & 7)) * 8);
      gl16(src, Kl + cK * 512);
    }
    {
      int p = tid & 31, dh = tid >> 5;
      const short* v0 = vb + (size_t)(b * cT + kt + 2 * p) * 512 + kvh * 64 + dh * 16;
      const short* v1 = v0 + 512;
      sh8 a0 = *(const sh8*)v0, a1 = *(const sh8*)(v0 + 8);
      sh8 c0 = *(const sh8*)v1, c1 = *(const sh8*)(v1 + 8);
      #pragma unroll
      for (int j = 0; j < 16; j++) {
        int d = dh * 16 + j;
        unsigned lo = (unsigned)(unsigned short)(j < 8 ? a0[j] : a1[j - 8]);
        unsigned hi = (unsigned)(unsigned short)(j < 8 ? c0[j] : c1[j - 8]);
        *(unsigned*)((char*)Vt + d * 128 + ((p * 4) ^ ((d & 7) << 4))) = lo | (hi << 16);
      }
    }
    __syncthreads();

    f16x s0 = {}, s1 = {};
    #pragma unroll
    for (int k = 0; k < 4; k++) {
      int o16 = k * 2 + g;
      sh8 b0 = *(sh8*)((char*)Kl + c * 128 + ((o16 ^ (c & 7)) * 16));
      sh8 b1 = *(sh8*)((char*)Kl + (32 + c) * 128 + ((o16 ^ ((32 + c) & 7)) * 16));
      s0 = __builtin_amdgcn_mfma_f32_32x32x16_bf16(aq[k], b0, s0, 0, 0, 0);
      s1 = __builtin_amdgcn_mfma_f32_32x32x16_bf16(aq[k], b1, s1, 0, 0, 0);
    }
    #pragma unroll
    for (int i = 0; i < 16; i++) { s0[i] *= 0.125f; s1[i] *= 0.125f; }

    if (kt + 63 > qb0 + w * 32) {
      #pragma unroll
      for (int i = 0; i < 16; i++) {
        int r = qb0 + w * 32 + (i & 3) + 8 * (i >> 2) + 4 * g;
        if (kt + c > r)      s0[i] = -1e30f;
        if (kt + 32 + c > r) s1[i] = -1e30f;
      }
    }

    #pragma unroll
    for (int i = 0; i < 16; i++) {
      float mt = fmaxf(s0[i], s1[i]);
      #pragma unroll
      for (int off = 1; off < 32; off <<= 1) mt = fmaxf(mt, __shfl_xor(mt, off));
      float mn = fmaxf(m[i], mt);
      float rs = __expf(m[i] - mn);
      m[i] = mn;
      float p0 = __expf(s0[i] - mn);
      float p1 = __expf(s1[i] - mn);
      s0[i] = p0; s1[i] = p1;
      float ps = p0 + p1;
      #pragma unroll
      for (int off = 1; off < 32; off <<= 1) ps += __shfl_xor(ps, off);
      ll[i] = ll[i] * rs + ps;
      o0[i] *= rs; o1[i] *= rs;
    }

    #pragma unroll
    for (int i = 0; i < 16; i++) {
      int r = (i & 3) + 8 * (i >> 2) + 4 * g;
      *(short*)((char*)Pl[w] + r * 128 + ((c * 2) ^ ((r & 7) << 4)))        = f2bf(s0[i]);
      *(short*)((char*)Pl[w] + r * 128 + (((32 + c) * 2) ^ ((r & 7) << 4))) = f2bf(s1[i]);
    }

    #pragma unroll
    for (int k = 0; k < 4; k++) {
      int o16 = k * 2 + g;
      sh8 ap  = *(sh8*)((char*)Pl[w] + c * 128 + ((o16 ^ (c & 7)) * 16));
      sh8 bv0 = *(sh8*)((char*)Vt + c * 128 + ((o16 ^ (c & 7)) * 16));
      sh8 bv1 = *(sh8*)((char*)Vt + (32 + c) * 128 + ((o16 ^ ((32 + c) & 7)) * 16));
      o0 = __builtin_amdgcn_mfma_f32_32x32x16_bf16(ap, bv0, o0, 0, 0, 0);
      o1 = __builtin_amdgcn_mfma_f32_32x32x16_bf16(ap, bv1, o1, 0, 0, 0);
    }
  }

  #pragma unroll
  for (int i = 0; i < 16; i++) {
    int r = qb0 + w * 32 + (i & 3) + 8 * (i >> 2) + 4 * g;
    float inv = 1.0f / ll[i];
    short* yp = yb + (size_t)(b * cT + r) * cC + h * cHD;
    yp[c]      = f2bf(o0[i] * inv);
    yp[32 + c] = f2bf(o1[i] * inv);
  }
}

// ---------------- gate (bf16 h): top-2 + softmax + atomic routing ----------------
__global__ __launch_bounds__(256) void gate_k(const short* __restrict__ h2,
                                              const float* __restrict__ gw,
                                              float* __restrict__ selw,
                                              int* __restrict__ cnt, int* __restrict__ elist)
{
  int wv = threadIdx.x >> 6, lane = threadIdx.x & 63;
  int n = blockIdx.x * 4 + wv;
  float acc[8] = {0.f, 0.f, 0.f, 0.f, 0.f, 0.f, 0.f, 0.f};
  for (int c = lane; c < cC; c += 64) {
    float hv = bf2f(h2[(size_t)n * cC + c]);
    f4 g0 = *(const f4*)(gw + c * 8);
    f4 g1 = *(const f4*)(gw + c * 8 + 4);
    acc[0] = fmaf(hv, g0[0], acc[0]); acc[1] = fmaf(hv, g0[1], acc[1]);
    acc[2] = fmaf(hv, g0[2], acc[2]); acc[3] = fmaf(hv, g0[3], acc[3]);
    acc[4] = fmaf(hv, g1[0], acc[4]); acc[5] = fmaf(hv, g1[1], acc[5]);
    acc[6] = fmaf(hv, g1[2], acc[6]); acc[7] = fmaf(hv, g1[3], acc[7]);
  }
  #pragma unroll
  for (int e = 0; e < 8; e++)
    #pragma unroll
    for (int off = 32; off; off >>= 1) acc[e] += __shfl_xor(acc[e], off);
  if (lane == 0) {
    int i0 = 0; float m0 = acc[0];
    #pragma unroll
    for (int e = 1; e < 8; e++) if (acc[e] > m0) { m0 = acc[e]; i0 = e; }
    int i1 = -1; float m1 = -INFINITY;
    #pragma unroll
    for (int e = 0; e < 8; e++) if (e != i0 && acc[e] > m1) { m1 = acc[e]; i1 = e; }
    float e1 = expf(m1 - m0);
    selw[n * 2]     = 1.f / (1.f + e1);
    selw[n * 2 + 1] = e1 / (1.f + e1);
    int pos0 = atomicAdd(&cnt[i0], 1); elist[(size_t)i0 * cN + pos0] = n * 2;
    int pos1 = atomicAdd(&cnt[i1], 1); elist[(size_t)i1 * cN + pos1] = n * 2 + 1;
  }
}

// ---------------- logits (bf16 h, fp32 wte) ----------------
__global__ __launch_bounds__(256) void logits_k(const short* __restrict__ hf,
                                                const float* __restrict__ wte,
                                                float* __restrict__ out)
{
  int wv = threadIdx.x >> 6, lane = threadIdx.x & 63;
  int v = blockIdx.x * 4 + wv;
  const float* wrow = wte + (size_t)v * cC;
  const short* r0 = hf + (size_t)(cT - 1) * cC;
  const short* r1 = hf + (size_t)(2 * cT - 1) * cC;
  float a0 = 0.f, a1 = 0.f;
  for (int c = lane * 4; c < cC; c += 256) {
    f4 w4 = *(const f4*)(wrow + c);
    sh4 s0 = *(const sh4*)(r0 + c);
    sh4 s1 = *(const sh4*)(r1 + c);
    #pragma unroll
    for (int j = 0; j < 4; j++) {
      a0 = fmaf(w4[j], bf2f(s0[j]), a0);
      a1 = fmaf(w4[j], bf2f(s1[j]), a1);
    }
  }
  #pragma unroll
  for (int off = 32; off; off >>= 1) { a0 += __shfl_xor(a0, off); a1 += __shfl_xor(a1, off); }
  if (lane == 0) { out[v] = a0; out[cV + v] = a1; }
}

// =======================================================================
extern "C" void kernel_launch(void* const* d_in, const int* in_sizes, int n_in,
                              void* d_out, int out_size, void* d_ws, size_t ws_size,
                              hipStream_t stream)
{
  (void)in_sizes; (void)n_in; (void)out_size;
  const int*   idx  = (const int*)  d_in[0];
  const float* wte  = (const float*)d_in[1];
  const float* ln1w = (const float*)d_in[2];
  const float* p_wq = (const float*)d_in[3];
  const float* p_wk = (const float*)d_in[4];
  const float* p_wv = (const float*)d_in[5];
  const float* p_wo = (const float*)d_in[6];
  const float* ln2w = (const float*)d_in[7];
  const float* gw   = (const float*)d_in[8];
  const float* w1   = (const float*)d_in[9];
  const float* w2   = (const float*)d_in[10];
  const float* w3   = (const float*)d_in[11];
  const float* lnfw = (const float*)d_in[12];
  float* out = (float*)d_out;

  char* base = (char*)d_ws;
  size_t off = 0;
  auto alloc = [&](size_t bytes) { char* r = base + off; off = (off + bytes + 255) & ~(size_t)255; return r; };

  float* x     = (float*)alloc((size_t)cN * cC * 4);
  short* h     = (short*)alloc((size_t)cN * cC * 2);
  short* q     = (short*)alloc((size_t)cN * cC * 2);
  short* kbuf  = (short*)alloc((size_t)cN * 512 * 2);
  short* vbuf  = (short*)alloc((size_t)cN * 512 * 2);
  short* y     = (short*)alloc((size_t)cN * cC * 2);
  short* acts  = (short*)alloc((size_t)cN * 2 * cHIDP * 2);
  float* selw  = (float*)alloc((size_t)cN * 2 * 4);
  int*   cnt   = (int*)  alloc(64);
  int*   elist = (int*)  alloc((size_t)cE * cN * 4);
  short* wqkvT = (short*)alloc((size_t)2 * 2048 * 1024 * 2);
  short* woT   = (short*)alloc((size_t)2 * 1024 * 1024 * 2);
  short* w1T   = (short*)alloc((size_t)cE * cHIDR * 1024 * 2);
  short* w3T   = (short*)alloc((size_t)cE * cHIDR * 1024 * 2);
  short* w2T   = (short*)alloc((size_t)cE * 1024 * cHIDP * 2);
  if (ws_size < off) return;   // ~183 MB

  embed_k<<<cN, 256, 0, stream>>>(idx, wte, x);
  convT_k<<<dim3(32, 32, 2), 256, 0, stream>>>(p_wq, wqkvT, 1024, 1024, 1024,
      (size_t)1024 * 1024, (size_t)2048 * 1024);
  convT_k<<<dim3(32, 16, 2), 256, 0, stream>>>(p_wk, wqkvT + (size_t)1024 * 1024, 1024, 512, 1024,
      (size_t)1024 * 512, (size_t)2048 * 1024);
  convT_k<<<dim3(32, 16, 2), 256, 0, stream>>>(p_wv, wqkvT + (size_t)1536 * 1024, 1024, 512, 1024,
      (size_t)1024 * 512, (size_t)2048 * 1024);
  convT_k<<<dim3(32, 32, 2), 256, 0, stream>>>(p_wo, woT, 1024, 1024, 1024,
      (size_t)1024 * 1024, (size_t)1024 * 1024);

  for (int l = 0; l < 2; l++) {
    // ---- attention ----
    rmsnorm_k<<<cN, 256, 0, stream>>>(x, ln1w + (size_t)l * cC, h);
    ggemm<2><<<dim3(16, 16), 256, 0, stream>>>(h, wqkvT + (size_t)l * 2048 * 1024,
        nullptr, q, kbuf, vbuf, cN, 2048, 1024, 1024, 1024, 0);
    rope_k<<<(cN * cNH * 32) / 256, 256, 0, stream>>>(q, cNH);
    rope_k<<<(cN * cNKV * 32) / 256, 256, 0, stream>>>(kbuf, cNKV);
    attn_k<<<dim3(16, cNH, cB), 128, 0, stream>>>(q, kbuf, vbuf, y);
    ggemm<1><<<dim3(16, 8), 256, 0, stream>>>(y, woT + (size_t)l * 1024 * 1024,
        x, nullptr, nullptr, nullptr, cN, 1024, 1024, 1024, 1024, 1024);

    // ---- MoE (producer->consumer adjacency kept from r9) ----
    rmsnorm_k<<<cN, 256, 0, stream>>>(x, ln2w + (size_t)l * cC, h);
    hipMemsetAsync(cnt, 0, cE * sizeof(int), stream);
    gate_k<<<cN / 4, 256, 0, stream>>>(h, gw + (size_t)l * cC * cE, selw, cnt, elist);
    convT_k<<<dim3(32, 86, 8), 256, 0, stream>>>(w1 + (size_t)l * cE * cC * cHID, w1T,
        1024, cHID, 1024, (size_t)1024 * cHID, (size_t)cHIDR * 1024);
    convT_k<<<dim3(32, 86, 8), 256, 0, stream>>>(w3 + (size_t)l * cE * cC * cHID, w3T,
        1024, cHID, 1024, (size_t)1024 * cHID, (size_t)cHIDR * 1024);
    gg_ff<<<dim3(32, 22, 8), 256, 0, stream>>>(h, w1T, w3T, acts, elist, cnt);
    convT_k<<<dim3(86, 32, 8), 256, 0, stream>>>(w2 + (size_t)l * cE * cHID * cC, w2T,
        cHID, 1024, cHIDP, (size_t)cHID * 1024, (size_t)1024 * cHIDP);
    gg_w2<<<dim3(32, 8, 16), 256, 0, stream>>>(acts, w2T, x, selw, elist, cnt);
  }

  rmsnorm_k<<<cN, 256, 0, stream>>>(x, lnfw, h);
  logits_k<<<cV / 4, 256, 0, stream>>>(h, wte, out);
}

// Round 13
// 1179.345 us; speedup vs baseline: 1.3934x; 1.0707x over previous
//
#include <hip/hip_runtime.h>
#include <hip/hip_bf16.h>
#include <math.h>

using f4 = __attribute__((ext_vector_type(4))) float;
using f16x = __attribute__((ext_vector_type(16))) float;
using sh4 = __attribute__((ext_vector_type(4))) short;
using sh8 = __attribute__((ext_vector_type(8))) short;

constexpr int cV = 32000, cC = 1024;
constexpr int cNH = 16, cNKV = 8, cHD = 64;
constexpr int cE = 8, cHID = 2728;
constexpr int cHIDP = 2752;              // K-pad for w2 (multiple of 64)
constexpr int cHIDR = 2816;              // row-pad for w1T/w3T slabs
constexpr int cB = 2, cT = 1024, cN = cB * cT;

__device__ inline float dot4(f4 a, f4 b) { return a[0]*b[0] + a[1]*b[1] + a[2]*b[2] + a[3]*b[3]; }

__device__ inline short f2bf(float f) {
  unsigned u = __builtin_bit_cast(unsigned, f);
  u += 0x7fff + ((u >> 16) & 1);          // RNE
  return (short)(u >> 16);
}
__device__ inline float bf2f(short s) {
  return __builtin_bit_cast(float, ((unsigned)(unsigned short)s) << 16);
}

// async global->LDS, 16B per lane; LDS dest is wave-uniform base + lane*16 (m97).
__device__ __forceinline__ void gl16(const void* g, void* l) {
  __builtin_amdgcn_global_load_lds((const __attribute__((address_space(1))) void*)g,
                                   (__attribute__((address_space(3))) void*)l, 16, 0, 0);
}

// ---- 64x64 transpose+convert tile body: src[K][N] fp32 -> dst[N][Kp] bf16 ----
__device__ __forceinline__ void convT64(const float* __restrict__ src, short* __restrict__ dst,
                                        int K, int N, int Kp, int k0, int n0, float* T /*64x65*/)
{
  int r = threadIdx.x >> 4;              // 0..15
  int cq = (threadIdx.x & 15) * 4;       // 0..60
  #pragma unroll
  for (int j = 0; j < 4; j++) {
    int k = k0 + r + j * 16;
    f4 v = {0.f, 0.f, 0.f, 0.f};
    if (k < K && n0 + cq < N)            // N%4==0 -> full f4 or none
      v = *(const f4*)(src + (size_t)k * N + n0 + cq);
    T[(r + j * 16) * 65 + cq + 0] = v[0];
    T[(r + j * 16) * 65 + cq + 1] = v[1];
    T[(r + j * 16) * 65 + cq + 2] = v[2];
    T[(r + j * 16) * 65 + cq + 3] = v[3];
  }
  __syncthreads();
  #pragma unroll
  for (int j = 0; j < 4; j++) {
    int n = n0 + r + j * 16;
    if (n < N) {
      sh4 ov = { f2bf(T[(cq + 0) * 65 + r + j * 16]), f2bf(T[(cq + 1) * 65 + r + j * 16]),
                 f2bf(T[(cq + 2) * 65 + r + j * 16]), f2bf(T[(cq + 3) * 65 + r + j * 16]) };
      *(sh4*)(dst + (size_t)n * Kp + k0 + cq) = ov;
    }
  }
}

// ---------------- embedding gather ----------------
__global__ void embed_k(const int* __restrict__ idx, const float* __restrict__ wte,
                        float* __restrict__ x)
{
  int n = blockIdx.x, tid = threadIdx.x;
  size_t row = (size_t)idx[n] * cC;
  *(f4*)(x + (size_t)n * cC + tid * 4) = *(const f4*)(wte + row + tid * 4);
}

// ---------------- rmsnorm (fp32 in, bf16 out) ----------------
__global__ __launch_bounds__(256) void rmsnorm_k(const float* __restrict__ in,
                                                 const float* __restrict__ w,
                                                 short* __restrict__ out)
{
  int n = blockIdx.x, tid = threadIdx.x;
  f4 v = *(const f4*)(in + (size_t)n * cC + tid * 4);
  float s = dot4(v, v);
  #pragma unroll
  for (int off = 32; off; off >>= 1) s += __shfl_xor(s, off);
  __shared__ float red[4];
  if ((tid & 63) == 0) red[tid >> 6] = s;
  __syncthreads();
  float tot = red[0] + red[1] + red[2] + red[3];
  float inv = rsqrtf(tot * (1.0f / cC) + 1e-5f);
  f4 wv = *(const f4*)(w + tid * 4);
  f4 o = v * inv * wv;
  sh4 ov = { f2bf(o[0]), f2bf(o[1]), f2bf(o[2]), f2bf(o[3]) };
  *(sh4*)(out + (size_t)n * cC + tid * 4) = ov;
}

// ------- final rmsnorm: ONLY the last row per batch (logits needs 2 rows) -------
__global__ __launch_bounds__(256) void rmsnorm2_k(const float* __restrict__ in,
                                                  const float* __restrict__ w,
                                                  short* __restrict__ out)
{
  int n = (blockIdx.x == 0) ? (cT - 1) : (2 * cT - 1);
  int tid = threadIdx.x;
  f4 v = *(const f4*)(in + (size_t)n * cC + tid * 4);
  float s = dot4(v, v);
  #pragma unroll
  for (int off = 32; off; off >>= 1) s += __shfl_xor(s, off);
  __shared__ float red[4];
  if ((tid & 63) == 0) red[tid >> 6] = s;
  __syncthreads();
  float tot = red[0] + red[1] + red[2] + red[3];
  float inv = rsqrtf(tot * (1.0f / cC) + 1e-5f);
  f4 wv = *(const f4*)(w + tid * 4);
  f4 o = v * inv * wv;
  sh4 ov = { f2bf(o[0]), f2bf(o[1]), f2bf(o[2]), f2bf(o[3]) };
  *(sh4*)(out + (size_t)blockIdx.x * cC + tid * 4) = ov;
}

// ---- fused rmsnorm(ln2) + gate: bf16 h out, top-2 softmax routing ----
__global__ __launch_bounds__(256) void rmsnorm_gate_k(
    const float* __restrict__ in, const float* __restrict__ w, const float* __restrict__ gw,
    short* __restrict__ out, float* __restrict__ selw,
    int* __restrict__ cnt, int* __restrict__ elist)
{
  int n = blockIdx.x, tid = threadIdx.x;
  f4 v = *(const f4*)(in + (size_t)n * cC + tid * 4);
  float s = dot4(v, v);
  #pragma unroll
  for (int off = 32; off; off >>= 1) s += __shfl_xor(s, off);
  __shared__ float red[4];
  __shared__ float red2[4][8];
  if ((tid & 63) == 0) red[tid >> 6] = s;
  __syncthreads();
  float tot = red[0] + red[1] + red[2] + red[3];
  float inv = rsqrtf(tot * (1.0f / cC) + 1e-5f);
  f4 wv = *(const f4*)(w + tid * 4);
  f4 o = v * inv * wv;
  sh4 ov = { f2bf(o[0]), f2bf(o[1]), f2bf(o[2]), f2bf(o[3]) };
  *(sh4*)(out + (size_t)n * cC + tid * 4) = ov;
  // gate logits: this thread's 4 channels (c = tid*4 + j)
  float acc[8] = {};
  #pragma unroll
  for (int j = 0; j < 4; j++) {
    const float* gr = gw + (size_t)(tid * 4 + j) * 8;
    f4 g0 = *(const f4*)gr, g1 = *(const f4*)(gr + 4);
    acc[0] = fmaf(o[j], g0[0], acc[0]); acc[1] = fmaf(o[j], g0[1], acc[1]);
    acc[2] = fmaf(o[j], g0[2], acc[2]); acc[3] = fmaf(o[j], g0[3], acc[3]);
    acc[4] = fmaf(o[j], g1[0], acc[4]); acc[5] = fmaf(o[j], g1[1], acc[5]);
    acc[6] = fmaf(o[j], g1[2], acc[6]); acc[7] = fmaf(o[j], g1[3], acc[7]);
  }
  #pragma unroll
  for (int e = 0; e < 8; e++)
    #pragma unroll
    for (int off = 32; off; off >>= 1) acc[e] += __shfl_xor(acc[e], off);
  if ((tid & 63) == 0)
    #pragma unroll
    for (int e = 0; e < 8; e++) red2[tid >> 6][e] = acc[e];
  __syncthreads();
  if (tid == 0) {
    float lg[8];
    #pragma unroll
    for (int e = 0; e < 8; e++) lg[e] = red2[0][e] + red2[1][e] + red2[2][e] + red2[3][e];
    int i0 = 0; float m0 = lg[0];
    #pragma unroll
    for (int e = 1; e < 8; e++) if (lg[e] > m0) { m0 = lg[e]; i0 = e; }
    int i1 = -1; float m1 = -INFINITY;
    #pragma unroll
    for (int e = 0; e < 8; e++) if (e != i0 && lg[e] > m1) { m1 = lg[e]; i1 = e; }
    float e1 = expf(m1 - m0);
    selw[n * 2]     = 1.f / (1.f + e1);
    selw[n * 2 + 1] = e1 / (1.f + e1);
    int pos0 = atomicAdd(&cnt[i0], 1); elist[(size_t)i0 * cN + pos0] = n * 2;
    int pos1 = atomicAdd(&cnt[i1], 1); elist[(size_t)i1 * cN + pos1] = n * 2 + 1;
  }
}

// ---- upfront merged convT for wq/wk/wv/wo (1536 blocks, 64x64 tiles) ----
__global__ __launch_bounds__(256) void convT4_k(
    const float* __restrict__ wq, const float* __restrict__ wk,
    const float* __restrict__ wv, const float* __restrict__ wo,
    short* __restrict__ wqkvT, short* __restrict__ woT)
{
  __shared__ float T[64 * 65];
  int bid = blockIdx.x;
  const float* src; short* dst; int N, kx, ny, z;
  if (bid < 512) {                       // wq: 16k x 16n x 2L
    kx = bid & 15; ny = (bid >> 4) & 15; z = bid >> 8;
    src = wq + (size_t)z * 1024 * 1024; dst = wqkvT + (size_t)z * 2048 * 1024; N = 1024;
  } else if (bid < 768) {                // wk: 16 x 8 x 2
    int r = bid - 512; kx = r & 15; ny = (r >> 4) & 7; z = r >> 7;
    src = wk + (size_t)z * 1024 * 512;
    dst = wqkvT + (size_t)z * 2048 * 1024 + (size_t)1024 * 1024; N = 512;
  } else if (bid < 1024) {               // wv
    int r = bid - 768; kx = r & 15; ny = (r >> 4) & 7; z = r >> 7;
    src = wv + (size_t)z * 1024 * 512;
    dst = wqkvT + (size_t)z * 2048 * 1024 + (size_t)1536 * 1024; N = 512;
  } else {                               // wo: 16 x 16 x 2
    int r = bid - 1024; kx = r & 15; ny = (r >> 4) & 15; z = r >> 8;
    src = wo + (size_t)z * 1024 * 1024; dst = woT + (size_t)z * 1024 * 1024; N = 1024;
  }
  convT64(src, dst, 1024, N, 1024, kx * 64, ny * 64, T);
}

// ====== merged QKV GEMM + convT(w1,w3,w2) — fills BW under the latency-bound GEMM ======
// 1D grid: [0,256) qkv 128x128 tiles; then w1 (16x43x8), w3, w2 (43x16x8) conv tiles.
__global__ __launch_bounds__(256, 3) void qkv_conv_k(
    const short* __restrict__ Ab, const short* __restrict__ Bt,
    short* __restrict__ Cq, short* __restrict__ Ck, short* __restrict__ Cv,
    const float* __restrict__ w1, const float* __restrict__ w3, const float* __restrict__ w2,
    short* __restrict__ w1T, short* __restrict__ w3T, short* __restrict__ w2T)
{
  __shared__ short smem[2 * 128 * 64];   // 32KB: gemm As|Bs; convT reuses as float T
  int bid = blockIdx.x;
  if (bid >= 256) {
    float* T = (float*)smem;
    int rem = bid - 256;
    if (rem < 11008) {                   // w1 / w3: K=1024(16), N=2728(43), 8 experts
      const float* src = (rem < 5504) ? w1 : w3;
      short* dst = (rem < 5504) ? w1T : w3T;
      int r = (rem < 5504) ? rem : rem - 5504;
      int kx = r % 16; r /= 16;
      int ny = r % 43; int e = r / 43;
      convT64(src + (size_t)e * 1024 * cHID, dst + (size_t)e * cHIDR * 1024,
              1024, cHID, 1024, kx * 64, ny * 64, T);
    } else {                             // w2: K=2728(43), N=1024(16), 8 experts
      int r = rem - 11008;
      int kx = r % 43; r /= 43;
      int ny = r % 16; int e = r / 16;
      convT64(w2 + (size_t)e * (size_t)cHID * 1024, w2T + (size_t)e * 1024 * cHIDP,
              cHID, 1024, cHIDP, kx * 64, ny * 64, T);
    }
    return;
  }
  // ---- qkv: dense 128x128 tile, single-buffer (r9 ggemm<2,0> body) ----
  short* As = smem;
  short* Bs = smem + 8192;
  int m0 = (bid & 15) * 128;
  int n0 = (bid >> 4) * 128;
  constexpr int K = 1024, lda = 1024, ldb = 1024;

  int tid = threadIdx.x, l = tid & 63, w = tid >> 6;
  int wr = w >> 1, wc = w & 1;
  int lq = l >> 3, ls = l & 7;

  const short* aptr[4];
  const short* bptr[4];
  #pragma unroll
  for (int i = 0; i < 4; i++) {
    int cA = w * 4 + i;
    int rA = cA * 8 + lq;
    int swz = (ls ^ (rA & 7)) * 8;
    aptr[i] = Ab + (size_t)(m0 + rA) * lda + swz;
    bptr[i] = Bt + (size_t)(n0 + rA) * ldb + swz;
  }

  f4 acc[4][4] = {};
  int fr = l & 15, fq = l >> 4;

  for (int k0 = 0; k0 < K; k0 += 64) {
    #pragma unroll
    for (int i = 0; i < 4; i++) {
      gl16(aptr[i] + k0, As + (w * 4 + i) * 512);
      gl16(bptr[i] + k0, Bs + (w * 4 + i) * 512);
    }
    __syncthreads();
    #pragma unroll
    for (int kk = 0; kk < 2; kk++) {
      sh8 af[4], bf[4];
      #pragma unroll
      for (int m = 0; m < 4; m++) {
        int r = wr * 64 + m * 16 + fr;
        af[m] = *(const sh8*)(As + r * 64 + (((kk * 4 + fq) ^ (r & 7)) * 8));
      }
      #pragma unroll
      for (int n = 0; n < 4; n++) {
        int r = wc * 64 + n * 16 + fr;
        bf[n] = *(const sh8*)(Bs + r * 64 + (((kk * 4 + fq) ^ (r & 7)) * 8));
      }
      #pragma unroll
      for (int m = 0; m < 4; m++)
        #pragma unroll
        for (int n = 0; n < 4; n++)
          acc[m][n] = __builtin_amdgcn_mfma_f32_16x16x32_bf16(af[m], bf[n], acc[m][n], 0, 0, 0);
    }
    __syncthreads();
  }

  int rq = fq * 4;
  #pragma unroll
  for (int m = 0; m < 4; m++) {
    #pragma unroll
    for (int i = 0; i < 4; i++) {
      size_t crow = (size_t)(m0 + wr * 64 + m * 16 + rq + i);
      #pragma unroll
      for (int n = 0; n < 4; n++) {
        int ncol = n0 + wc * 64 + n * 16 + fr;
        short s = f2bf(acc[m][n][i]);
        if (ncol < 1024)      Cq[crow * 1024 + ncol] = s;
        else if (ncol < 1536) Ck[crow * 512 + (ncol - 1024)] = s;
        else                  Cv[crow * 512 + (ncol - 1536)] = s;
      }
    }
  }
}

// ====== m97-style bf16 GEMM (r9): 128x128, BK=64, single-buffer, swizzled ======
// EPI: 0 f32 store, 1 f32 +=.  GATH: 0 dense, 2 A/C row = list[m].
template<int EPI, int GATH>
__global__ __launch_bounds__(256, 3) void ggemm(
    const short* __restrict__ Ab, const short* __restrict__ Bt,
    float* __restrict__ Cf,
    int M, int Nc, int K, int lda, int ldb, int ldc, size_t bz,
    const int* __restrict__ gidx, const int* __restrict__ gcnt)
{
  int Me = M;
  const int* idxp = nullptr;
  const short* Bte = Bt;
  if (GATH) {
    int e = blockIdx.z;
    Me = gcnt[e];
    idxp = gidx + (size_t)e * cN;
    Bte += (size_t)e * bz;
  }
  int m0 = blockIdx.x * 128;
  if (m0 >= Me) return;
  int n0 = blockIdx.y * 128;

  __shared__ short As[128 * 64];
  __shared__ short Bs[128 * 64];

  int tid = threadIdx.x, l = tid & 63, w = tid >> 6;
  int wr = w >> 1, wc = w & 1;
  int lq = l >> 3, ls = l & 7;

  const short* aptr[4];
  const short* bptr[4];
  #pragma unroll
  for (int i = 0; i < 4; i++) {
    int cA = w * 4 + i;
    int rA = cA * 8 + lq;
    int arow;
    if (GATH) { int mr = m0 + rA; if (mr >= Me) mr = Me - 1; arow = idxp[mr]; }
    else arow = m0 + rA;
    int swz = (ls ^ (rA & 7)) * 8;
    aptr[i] = Ab + (size_t)arow * lda + swz;
    bptr[i] = Bte + (size_t)(n0 + rA) * ldb + swz;
  }

  f4 acc[4][4] = {};
  int fr = l & 15, fq = l >> 4;

  for (int k0 = 0; k0 < K; k0 += 64) {
    #pragma unroll
    for (int i = 0; i < 4; i++) {
      gl16(aptr[i] + k0, As + (w * 4 + i) * 512);
      gl16(bptr[i] + k0, Bs + (w * 4 + i) * 512);
    }
    __syncthreads();
    #pragma unroll
    for (int kk = 0; kk < 2; kk++) {
      sh8 af[4], bf[4];
      #pragma unroll
      for (int m = 0; m < 4; m++) {
        int r = wr * 64 + m * 16 + fr;
        af[m] = *(const sh8*)(As + r * 64 + (((kk * 4 + fq) ^ (r & 7)) * 8));
      }
      #pragma unroll
      for (int n = 0; n < 4; n++) {
        int r = wc * 64 + n * 16 + fr;
        bf[n] = *(const sh8*)(Bs + r * 64 + (((kk * 4 + fq) ^ (r & 7)) * 8));
      }
      #pragma unroll
      for (int m = 0; m < 4; m++)
        #pragma unroll
        for (int n = 0; n < 4; n++)
          acc[m][n] = __builtin_amdgcn_mfma_f32_16x16x32_bf16(af[m], bf[n], acc[m][n], 0, 0, 0);
    }
    __syncthreads();
  }

  int rq = fq * 4;
  #pragma unroll
  for (int m = 0; m < 4; m++) {
    #pragma unroll
    for (int i = 0; i < 4; i++) {
      int mrow = m0 + wr * 64 + m * 16 + rq + i;
      if (GATH && mrow >= Me) continue;
      size_t crow = (size_t)(GATH ? idxp[mrow] : mrow);
      #pragma unroll
      for (int n = 0; n < 4; n++) {
        int ncol = n0 + wc * 64 + n * 16 + fr;
        float vv = acc[m][n][i];
        if (EPI == 0) Cf[crow * ldc + ncol] = vv;
        else          Cf[crow * ldc + ncol] += vv;
      }
    }
  }
}

// ====== fused w1+w3 gather GEMM (r9): acts = silu(h@w1)*(h@w3), bf16 ======
__global__ __launch_bounds__(256, 2) void gg_ff(
    const short* __restrict__ Ab, const short* __restrict__ B1t, const short* __restrict__ B3t,
    short* __restrict__ actsOut,
    const int* __restrict__ gidx, const int* __restrict__ gcnt)
{
  constexpr int K = cC, ldb = cC, lda = cC;
  int e = blockIdx.z;
  int Me = gcnt[e];
  const int* idxp = gidx + (size_t)e * cN;
  int m0 = blockIdx.x * 128;
  if (m0 >= Me) return;
  int n0 = blockIdx.y * 128;
  const short* B1e = B1t + (size_t)e * cHIDR * ldb;
  const short* B3e = B3t + (size_t)e * cHIDR * ldb;

  __shared__ short As[128 * 64];
  __shared__ short Bs1[128 * 64];
  __shared__ short Bs3[128 * 64];

  int tid = threadIdx.x, l = tid & 63, w = tid >> 6;
  int wr = w >> 1, wc = w & 1;
  int lq = l >> 3, ls = l & 7;

  const short* aptr[4];
  const short* b1ptr[4];
  const short* b3ptr[4];
  #pragma unroll
  for (int i = 0; i < 4; i++) {
    int cA = w * 4 + i;
    int rA = cA * 8 + lq;
    int mr = m0 + rA; if (mr >= Me) mr = Me - 1;
    int token = idxp[mr] >> 1;
    int swz = (ls ^ (rA & 7)) * 8;
    aptr[i]  = Ab + (size_t)token * lda + swz;
    b1ptr[i] = B1e + (size_t)(n0 + rA) * ldb + swz;
    b3ptr[i] = B3e + (size_t)(n0 + rA) * ldb + swz;
  }

  f4 acc1[4][4] = {}, acc3[4][4] = {};
  int fr = l & 15, fq = l >> 4;

  for (int k0 = 0; k0 < K; k0 += 64) {
    #pragma unroll
    for (int i = 0; i < 4; i++) {
      gl16(aptr[i] + k0,  As  + (w * 4 + i) * 512);
      gl16(b1ptr[i] + k0, Bs1 + (w * 4 + i) * 512);
      gl16(b3ptr[i] + k0, Bs3 + (w * 4 + i) * 512);
    }
    __syncthreads();
    #pragma unroll
    for (int kk = 0; kk < 2; kk++) {
      sh8 af[4], bf1[4], bf3[4];
      #pragma unroll
      for (int m = 0; m < 4; m++) {
        int r = wr * 64 + m * 16 + fr;
        af[m] = *(const sh8*)(As + r * 64 + (((kk * 4 + fq) ^ (r & 7)) * 8));
      }
      #pragma unroll
      for (int n = 0; n < 4; n++) {
        int r = wc * 64 + n * 16 + fr;
        int so = ((kk * 4 + fq) ^ (r & 7)) * 8;
        bf1[n] = *(const sh8*)(Bs1 + r * 64 + so);
        bf3[n] = *(const sh8*)(Bs3 + r * 64 + so);
      }
      #pragma unroll
      for (int m = 0; m < 4; m++)
        #pragma unroll
        for (int n = 0; n < 4; n++) {
          acc1[m][n] = __builtin_amdgcn_mfma_f32_16x16x32_bf16(af[m], bf1[n], acc1[m][n], 0, 0, 0);
          acc3[m][n] = __builtin_amdgcn_mfma_f32_16x16x32_bf16(af[m], bf3[n], acc3[m][n], 0, 0, 0);
        }
    }
    __syncthreads();
  }

  int rq = fq * 4;
  #pragma unroll
  for (int m = 0; m < 4; m++) {
    #pragma unroll
    for (int i = 0; i < 4; i++) {
      int mrow = m0 + wr * 64 + m * 16 + rq + i;
      if (mrow >= Me) continue;
      size_t crow = (size_t)idxp[mrow] * cHIDP;
      #pragma unroll
      for (int n = 0; n < 4; n++) {
        int ncol = n0 + wc * 64 + n * 16 + fr;
        if (ncol < cHID) {
          float a1 = acc1[m][n][i], a3 = acc3[m][n][i];
          actsOut[crow + ncol] = f2bf(a1 / (1.f + __expf(-a1)) * a3);
        } else if (ncol < cHIDP) {
          actsOut[crow + ncol] = 0;     // zero K-pad for w2
        }
      }
    }
  }
}

// ---------------- RoPE: q and k in one dispatch, bf16 in place ----------------
__global__ void rope_all_k(short* __restrict__ qb, short* __restrict__ kb)
{
  int gid = blockIdx.x * 256 + threadIdx.x;
  constexpr int QTOT = cN * cNH * 32;
  short* buf; int nh, g2;
  if (gid < QTOT) { buf = qb; nh = cNH; g2 = gid; }
  else            { buf = kb; nh = cNKV; g2 = gid - QTOT; }
  int i = g2 & 31;
  int rest = g2 >> 5;
  int h = rest % nh;
  int n = rest / nh;
  int t = n & (cT - 1);
  float fr = __expf(-(float)i * (9.210340371976184f / 32.f));
  float ang = (float)t * fr;
  float sn, cs;
  sincosf(ang, &sn, &cs);
  short* p = buf + (size_t)n * (nh * cHD) + h * cHD + 2 * i;
  float r0 = bf2f(p[0]), r1 = bf2f(p[1]);
  p[0] = f2bf(r0 * cs - r1 * sn);
  p[1] = f2bf(r0 * sn + r1 * cs);
}

// ======== MFMA flash attention (bf16 q/k/v): 64 q-rows, 2 waves x 32 ========
__global__ __launch_bounds__(128) void attn_k(const short* __restrict__ qb,
                                              const short* __restrict__ kb,
                                              const short* __restrict__ vb,
                                              short* __restrict__ yb)
{
  int h = blockIdx.y, b = blockIdx.z;
  int qt = (b == 1) ? (15 - blockIdx.x) : blockIdx.x;   // causal load balance
  int qb0 = qt * 64;
  int kvh = h >> 1;                        // n_rep = 2
  int tid = threadIdx.x, w = tid >> 6, l = tid & 63;
  int c = l & 31, g = l >> 5;

  __shared__ short Kl[64 * 64];
  __shared__ short Vt[64 * 64];
  __shared__ short Pl[2][32 * 64];

  sh8 aq[4];
  {
    const short* qp = qb + (size_t)(b * cT + qb0 + w * 32 + c) * cC + h * cHD + g * 8;
    #pragma unroll
    for (int k = 0; k < 4; k++) aq[k] = *(const sh8*)(qp + k * 16);
  }

  float m[16], ll[16];
  f16x o0 = {}, o1 = {};
  #pragma unroll
  for (int i = 0; i < 16; i++) { m[i] = -1e30f; ll[i] = 0.f; }

  for (int kt = 0; kt <= qb0; kt += 64) {
    __syncthreads();
    #pragma unroll
    for (int i = 0; i < 4; i++) {
      int cK = w * 4 + i;
      int rK = cK * 8 + (l >> 3);
      const short* src = kb + (size_t)(b * cT + kt + rK) * 512 + kvh * 64
                       + (((l & 7) ^ (rK & 7)) * 8);
      gl16(src, Kl + cK * 512);
    }
    {
      int p = tid & 31, dh = tid >> 5;
      const short* v0 = vb + (size_t)(b * cT + kt + 2 * p) * 512 + kvh * 64 + dh * 16;
      const short* v1 = v0 + 512;
      sh8 a0 = *(const sh8*)v0, a1 = *(const sh8*)(v0 + 8);
      sh8 c0 = *(const sh8*)v1, c1 = *(const sh8*)(v1 + 8);
      #pragma unroll
      for (int j = 0; j < 16; j++) {
        int d = dh * 16 + j;
        unsigned lo = (unsigned)(unsigned short)(j < 8 ? a0[j] : a1[j - 8]);
        unsigned hi = (unsigned)(unsigned short)(j < 8 ? c0[j] : c1[j - 8]);
        *(unsigned*)((char*)Vt + d * 128 + ((p * 4) ^ ((d & 7) << 4))) = lo | (hi << 16);
      }
    }
    __syncthreads();

    f16x s0 = {}, s1 = {};
    #pragma unroll
    for (int k = 0; k < 4; k++) {
      int o16 = k * 2 + g;
      sh8 b0 = *(sh8*)((char*)Kl + c * 128 + ((o16 ^ (c & 7)) * 16));
      sh8 b1 = *(sh8*)((char*)Kl + (32 + c) * 128 + ((o16 ^ ((32 + c) & 7)) * 16));
      s0 = __builtin_amdgcn_mfma_f32_32x32x16_bf16(aq[k], b0, s0, 0, 0, 0);
      s1 = __builtin_amdgcn_mfma_f32_32x32x16_bf16(aq[k], b1, s1, 0, 0, 0);
    }
    #pragma unroll
    for (int i = 0; i < 16; i++) { s0[i] *= 0.125f; s1[i] *= 0.125f; }

    if (kt + 63 > qb0 + w * 32) {
      #pragma unroll
      for (int i = 0; i < 16; i++) {
        int r = qb0 + w * 32 + (i & 3) + 8 * (i >> 2) + 4 * g;
        if (kt + c > r)      s0[i] = -1e30f;
        if (kt + 32 + c > r) s1[i] = -1e30f;
      }
    }

    #pragma unroll
    for (int i = 0; i < 16; i++) {
      float mt = fmaxf(s0[i], s1[i]);
      #pragma unroll
      for (int off = 1; off < 32; off <<= 1) mt = fmaxf(mt, __shfl_xor(mt, off));
      float mn = fmaxf(m[i], mt);
      float rs = __expf(m[i] - mn);
      m[i] = mn;
      float p0 = __expf(s0[i] - mn);
      float p1 = __expf(s1[i] - mn);
      s0[i] = p0; s1[i] = p1;
      float ps = p0 + p1;
      #pragma unroll
      for (int off = 1; off < 32; off <<= 1) ps += __shfl_xor(ps, off);
      ll[i] = ll[i] * rs + ps;
      o0[i] *= rs; o1[i] *= rs;
    }

    #pragma unroll
    for (int i = 0; i < 16; i++) {
      int r = (i & 3) + 8 * (i >> 2) + 4 * g;
      *(short*)((char*)Pl[w] + r * 128 + ((c * 2) ^ ((r & 7) << 4)))        = f2bf(s0[i]);
      *(short*)((char*)Pl[w] + r * 128 + (((32 + c) * 2) ^ ((r & 7) << 4))) = f2bf(s1[i]);
    }

    #pragma unroll
    for (int k = 0; k < 4; k++) {
      int o16 = k * 2 + g;
      sh8 ap  = *(sh8*)((char*)Pl[w] + c * 128 + ((o16 ^ (c & 7)) * 16));
      sh8 bv0 = *(sh8*)((char*)Vt + c * 128 + ((o16 ^ (c & 7)) * 16));
      sh8 bv1 = *(sh8*)((char*)Vt + (32 + c) * 128 + ((o16 ^ ((32 + c) & 7)) * 16));
      o0 = __builtin_amdgcn_mfma_f32_32x32x16_bf16(ap, bv0, o0, 0, 0, 0);
      o1 = __builtin_amdgcn_mfma_f32_32x32x16_bf16(ap, bv1, o1, 0, 0, 0);
    }
  }

  #pragma unroll
  for (int i = 0; i < 16; i++) {
    int r = qb0 + w * 32 + (i & 3) + 8 * (i >> 2) + 4 * g;
    float inv = 1.0f / ll[i];
    short* yp = yb + (size_t)(b * cT + r) * cC + h * cHD;
    yp[c]      = f2bf(o0[i] * inv);
    yp[32 + c] = f2bf(o1[i] * inv);
  }
}

// ---------------- weighted combine ----------------
__global__ void combine_k(float* __restrict__ x, const float* __restrict__ eo,
                          const float* __restrict__ selw)
{
  int n = blockIdx.x, tid = threadIdx.x;
  float w0 = selw[n * 2], w1 = selw[n * 2 + 1];
  f4 a = *(const f4*)(eo + (size_t)(n * 2) * cC + tid * 4);
  f4 b = *(const f4*)(eo + (size_t)(n * 2 + 1) * cC + tid * 4);
  f4 xv = *(f4*)(x + (size_t)n * cC + tid * 4);
  xv += a * w0 + b * w1;
  *(f4*)(x + (size_t)n * cC + tid * 4) = xv;
}

// ---------------- logits (compact 2-row bf16 h, fp32 wte) ----------------
__global__ __launch_bounds__(256) void logits_k(const short* __restrict__ hf,
                                                const float* __restrict__ wte,
                                                float* __restrict__ out)
{
  int wv = threadIdx.x >> 6, lane = threadIdx.x & 63;
  int v = blockIdx.x * 4 + wv;
  const float* wrow = wte + (size_t)v * cC;
  const short* r0 = hf;
  const short* r1 = hf + cC;
  float a0 = 0.f, a1 = 0.f;
  for (int c = lane * 4; c < cC; c += 256) {
    f4 w4 = *(const f4*)(wrow + c);
    sh4 s0 = *(const sh4*)(r0 + c);
    sh4 s1 = *(const sh4*)(r1 + c);
    #pragma unroll
    for (int j = 0; j < 4; j++) {
      a0 = fmaf(w4[j], bf2f(s0[j]), a0);
      a1 = fmaf(w4[j], bf2f(s1[j]), a1);
    }
  }
  #pragma unroll
  for (int off = 32; off; off >>= 1) { a0 += __shfl_xor(a0, off); a1 += __shfl_xor(a1, off); }
  if (lane == 0) { out[v] = a0; out[cV + v] = a1; }
}

// =======================================================================
extern "C" void kernel_launch(void* const* d_in, const int* in_sizes, int n_in,
                              void* d_out, int out_size, void* d_ws, size_t ws_size,
                              hipStream_t stream)
{
  (void)in_sizes; (void)n_in; (void)out_size;
  const int*   idx  = (const int*)  d_in[0];
  const float* wte  = (const float*)d_in[1];
  const float* ln1w = (const float*)d_in[2];
  const float* p_wq = (const float*)d_in[3];
  const float* p_wk = (const float*)d_in[4];
  const float* p_wv = (const float*)d_in[5];
  const float* p_wo = (const float*)d_in[6];
  const float* ln2w = (const float*)d_in[7];
  const float* gw   = (const float*)d_in[8];
  const float* w1   = (const float*)d_in[9];
  const float* w2   = (const float*)d_in[10];
  const float* w3   = (const float*)d_in[11];
  const float* lnfw = (const float*)d_in[12];
  float* out = (float*)d_out;

  char* base = (char*)d_ws;
  size_t off = 0;
  auto alloc = [&](size_t bytes) { char* r = base + off; off = (off + bytes + 255) & ~(size_t)255; return r; };

  float* x     = (float*)alloc((size_t)cN * cC * 4);
  short* h     = (short*)alloc((size_t)cN * cC * 2);
  short* q     = (short*)alloc((size_t)cN * cC * 2);
  short* kbuf  = (short*)alloc((size_t)cN * 512 * 2);
  short* vbuf  = (short*)alloc((size_t)cN * 512 * 2);
  short* y     = (short*)alloc((size_t)cN * cC * 2);
  short* acts  = (short*)alloc((size_t)cN * 2 * cHIDP * 2);
  float* eo    = (float*)alloc((size_t)cN * 2 * cC * 4);
  float* selw  = (float*)alloc((size_t)cN * 2 * 4);
  int*   cnt   = (int*)  alloc(64);
  int*   elist = (int*)  alloc((size_t)cE * cN * 4);
  short* wqkvT = (short*)alloc((size_t)2 * 2048 * 1024 * 2);
  short* woT   = (short*)alloc((size_t)2 * 1024 * 1024 * 2);
  short* w1T   = (short*)alloc((size_t)cE * cHIDR * 1024 * 2);
  short* w3T   = (short*)alloc((size_t)cE * cHIDR * 1024 * 2);
  short* w2T   = (short*)alloc((size_t)cE * 1024 * cHIDP * 2);
  if (ws_size < off) return;   // ~215 MB (fit demonstrated r5-r12)

  embed_k<<<cN, 256, 0, stream>>>(idx, wte, x);
  convT4_k<<<1536, 256, 0, stream>>>(p_wq, p_wk, p_wv, p_wo, wqkvT, woT);

  for (int l = 0; l < 2; l++) {
    // ---- attention + (overlapped) MoE weight conversion ----
    rmsnorm_k<<<cN, 256, 0, stream>>>(x, ln1w + (size_t)l * cC, h);
    hipMemsetAsync(cnt, 0, cE * sizeof(int), stream);
    qkv_conv_k<<<256 + 3 * 5504, 256, 0, stream>>>(h, wqkvT + (size_t)l * 2048 * 1024,
        q, kbuf, vbuf,
        w1 + (size_t)l * cE * cC * cHID, w3 + (size_t)l * cE * cC * cHID,
        w2 + (size_t)l * cE * (size_t)cHID * cC, w1T, w3T, w2T);
    rope_all_k<<<(cN * cNH * 32 + cN * cNKV * 32) / 256, 256, 0, stream>>>(q, kbuf);
    attn_k<<<dim3(16, cNH, cB), 128, 0, stream>>>(q, kbuf, vbuf, y);
    ggemm<1,0><<<dim3(16, 8), 256, 0, stream>>>(y, woT + (size_t)l * 1024 * 1024,
        x, cN, 1024, 1024, 1024, 1024, 1024, 0, nullptr, nullptr);

    // ---- MoE ----
    rmsnorm_gate_k<<<cN, 256, 0, stream>>>(x, ln2w + (size_t)l * cC, gw + (size_t)l * cC * cE,
        h, selw, cnt, elist);
    gg_ff<<<dim3(16, 22, 8), 256, 0, stream>>>(h, w1T, w3T, acts, elist, cnt);
    ggemm<0,2><<<dim3(16, 8, 8), 256, 0, stream>>>(acts, w2T, eo,
        0, 1024, cHIDP, cHIDP, cHIDP, 1024, (size_t)1024 * cHIDP, elist, cnt);
    combine_k<<<cN, 256, 0, stream>>>(x, eo, selw);
  }

  rmsnorm2_k<<<2, 256, 0, stream>>>(x, lnfw, h);
  logits_k<<<cV / 4, 256, 0, stream>>>(h, wte, out);
}